// Round 14
// baseline (162.148 us; speedup 1.0000x reference)
//
#include <hip/hip_runtime.h>
#include <hip/hip_bf16.h>
#include <math.h>
#include <stdint.h>

#define BB 256
#define LL 50
#define IDIM 128
#define PDIM 64
#define DIM 192
#define NITEMS 50000
#define NOUT 49999
#define WSC 20.0f
#define EPS 1e-5f
#define WMAT (DIM * DIM)

typedef __attribute__((ext_vector_type(8))) short  short8;
typedef __attribute__((ext_vector_type(4))) float  f32x4;

__device__ __forceinline__ unsigned short f2bf(float f) {
    unsigned int u = __float_as_uint(f);
    u = (u + 0x7FFFu + ((u >> 16) & 1u)) >> 16;
    return (unsigned short)u;
}
__device__ __forceinline__ float bf2f(unsigned short u) {
    unsigned int v = ((unsigned int)u) << 16;
    return __uint_as_float(v);
}

// ---------------- row norms of emb + bf16 copy ----------------
__global__ __launch_bounds__(256) void k_norms(const float* __restrict__ emb,
                                               float* __restrict__ scale,
                                               float* __restrict__ invn,
                                               unsigned short* __restrict__ emb16) {
    int row  = blockIdx.x * 4 + (threadIdx.x >> 6);
    int lane = threadIdx.x & 63;
    const float* p = emb + (size_t)row * IDIM;
    float a = p[lane], b = p[lane + 64];
    emb16[(size_t)row * IDIM + lane]      = f2bf(a);
    emb16[(size_t)row * IDIM + lane + 64] = f2bf(b);
    float s = a * a + b * b;
#pragma unroll
    for (int off = 32; off; off >>= 1) s += __shfl_xor(s, off);
    if (lane == 0) {
        float n = sqrtf(s);
        scale[row] = fminf(1.0f, 1.5f / fmaxf(n, 1e-7f));
        invn[row]  = (n > 0.f) ? 1.f / n : 0.f;
    }
}

__global__ __launch_bounds__(64) void k_pnorms(const float* __restrict__ pe,
                                               float* __restrict__ pscale) {
    int row = threadIdx.x;
    if (row > LL) return;
    float s = 0.f;
    const float* p = pe + row * PDIM;
    for (int d = 0; d < PDIM; ++d) { float v = p[d]; s += v * v; }
    float n = sqrtf(s);
    pscale[row] = fminf(1.0f, 1.5f / fmaxf(n, 1e-7f));
}

// ---------------- weight convert (+transpose for vw1,vw2) ----------------
// W16 layout: [0]=vw1^T [1]=vw2^T [2]=w1W [3]=w2W [4]=wg1W, each [n][k] 192x192
__global__ __launch_bounds__(256) void k_cvtw(const float* __restrict__ vw1, const float* __restrict__ vw2,
                                              const float* __restrict__ w1W, const float* __restrict__ w2W,
                                              const float* __restrict__ wg1W,
                                              unsigned short* __restrict__ Wout) {
    int b = blockIdx.x;
    int wi = b / 144;
    int pos = (b % 144) * 256 + threadIdx.x;
    int n = pos / DIM, k = pos - n * DIM;
    float v;
    if      (wi == 0) v = vw1[(size_t)k * DIM + n];
    else if (wi == 1) v = vw2[(size_t)k * DIM + n];
    else if (wi == 2) v = w1W[pos];
    else if (wi == 3) v = w2W[pos];
    else              v = wg1W[pos];
    Wout[(size_t)wi * WMAT + pos] = f2bf(v);
}

// ================= MEGAKERNEL (1024 threads = 16 waves) =================
__global__ __launch_bounds__(1024) void k_mega(
    const int* __restrict__ x, const int* __restrict__ pos,
    const float* __restrict__ emb, const float* __restrict__ pe,
    const float* __restrict__ scale, const float* __restrict__ pscale,
    const unsigned short* __restrict__ W16,
    const float* __restrict__ vw0, const float* __restrict__ vbias,
    const float* __restrict__ w1b, const float* __restrict__ w2b,
    const float* __restrict__ wg1b, const float* __restrict__ wg2W,
    const float* __restrict__ wg2b, const float* __restrict__ gq,
    const float* __restrict__ wA, const float* __restrict__ lng,
    const float* __restrict__ lnb, const float* __restrict__ wfW,
    const float* __restrict__ wfb, unsigned short* __restrict__ Cb16g) {

    __shared__ unsigned short Bs16[64 * DIM];   // swizzled: X16 -> S16 -> H16
    __shared__ unsigned short X16T[DIM * 72];   // X^T bf16 [d][j], cols 50..63 zero
    __shared__ unsigned short Ab16[64 * 72];    // attn weights bf16 [i][j]
    __shared__ float R1[LL * 196];              // K' -> parts[8][12][64]
    __shared__ float R2[LL * 196];              // Q -> S -> S2/S3
    __shared__ float xlast[DIM];
    __shared__ float GLs[DIM];
    __shared__ float cvec[3 * DIM];
    __shared__ float stB[DIM], sgB[DIM];
    __shared__ float red2[8][128];
    __shared__ float ags[64];
    __shared__ int   msk[64];
    __shared__ float was[64];
    __shared__ float red[16];
    __shared__ int   xi[LL], pii[LL];
    __shared__ float xsc[LL], psc[LL];

    const int b = blockIdx.x, t = threadIdx.x;
    const int wv = t >> 6, l = t & 63;
    const int lr = l & 15, lk = l >> 4;

    // ---- P0: indices, consts ----
    if (t < LL) {
        int v = x[b * LL + t];  xi[t] = v;  xsc[t] = scale[v];
        int pv = pos[b * LL + t]; pii[t] = pv; psc[t] = pscale[pv];
    }
    if (t >= 64 && t < 128) ags[t - 64] = 0.f;
    if (t >= 128 && t < 128 + LL) was[t - 128] = wA[t - 128];
    __syncthreads();
    if (t < 64) msk[t] = (t < LL) ? xi[t] : 0;
    // gather: wave per row, lane = d
    for (int r = wv; r < LL; r += 16) {
        float sx = xsc[r], sp = psc[r];
        float v0 = emb[(size_t)xi[r] * IDIM + l] * sx;
        float v1 = emb[(size_t)xi[r] * IDIM + l + 64] * sx;
        float v2 = pe[pii[r] * PDIM + l] * sp;
        int base = r * 384, sw = (r & 7) << 4;
        *(unsigned short*)((char*)Bs16 + ((base + l * 2) ^ sw))         = f2bf(v0);
        *(unsigned short*)((char*)Bs16 + ((base + (l + 64) * 2) ^ sw))  = f2bf(v1);
        *(unsigned short*)((char*)Bs16 + ((base + (l + 128) * 2) ^ sw)) = f2bf(v2);
        X16T[l * 72 + r]         = f2bf(v0);
        X16T[(l + 64) * 72 + r]  = f2bf(v1);
        X16T[(l + 128) * 72 + r] = f2bf(v2);
        if (r == 49) { xlast[l] = v0; xlast[l + 64] = v1; xlast[l + 128] = v2; }
    }
    // zero pads: Bs16 rows 50-63, X16T cols 50-63, Ab16 rows 50-63
    for (int e = t; e < 14 * DIM; e += 1024) Bs16[LL * DIM + e] = 0;
    for (int e = t; e < DIM * 14; e += 1024) { int d = e / 14, j = 50 + (e - d * 14); X16T[d * 72 + j] = 0; }
    for (int e = t; e < 14 * 72; e += 1024) Ab16[50 * 72 + e] = 0;
    __syncthreads();

    // ---- GL = xlast @ wg2W^T + wg2b ----
    if (t < DIM) {
        float g = wg2b[t];
        const float* wr = wg2W + (size_t)t * DIM;
        float s0 = 0, s1 = 0, s2 = 0, s3 = 0;
        for (int k = 0; k < DIM; k += 4) {
            float4 w4 = *(const float4*)(wr + k);
            s0 += xlast[k] * w4.x; s1 += xlast[k + 1] * w4.y;
            s2 += xlast[k + 2] * w4.z; s3 += xlast[k + 3] * w4.w;
        }
        GLs[t] = g + ((s0 + s1) + (s2 + s3));
    }
    __syncthreads();

    // ---- P1: three GEMMs sharing A = X16 (swizzled): K'->R1, Q->R2, Gpre->ags ----
    {
        short8 afr[4][6];
#pragma unroll
        for (int mt = 0; mt < 4; ++mt) {
            int row = mt * 16 + lr;
#pragma unroll
            for (int ks = 0; ks < 6; ++ks) {
                int byte = (row * 384 + (lk * 8 + ks * 32) * 2) ^ ((row & 7) << 4);
                afr[mt][ks] = *(const short8*)((const char*)Bs16 + byte);
            }
        }
        for (int task = wv; task < 36; task += 16) {
            int out = task / 12, nt = task % 12;
            int ncol = nt * 16 + lr;
            const unsigned short* bp = W16 + (size_t)(out == 0 ? 0 : (out == 1 ? 1 : 4)) * WMAT
                                       + (size_t)ncol * DIM + lk * 8;
            f32x4 a0 = {}, a1 = {}, a2 = {}, a3 = {};
#pragma unroll
            for (int ks = 0; ks < 6; ++ks) {
                short8 bf = *(const short8*)(bp + ks * 32);
                a0 = __builtin_amdgcn_mfma_f32_16x16x32_bf16(afr[0][ks], bf, a0, 0, 0, 0);
                a1 = __builtin_amdgcn_mfma_f32_16x16x32_bf16(afr[1][ks], bf, a1, 0, 0, 0);
                a2 = __builtin_amdgcn_mfma_f32_16x16x32_bf16(afr[2][ks], bf, a2, 0, 0, 0);
                a3 = __builtin_amdgcn_mfma_f32_16x16x32_bf16(afr[3][ks], bf, a3, 0, 0, 0);
            }
            if (out == 0) {
                float bia = vbias[ncol];
#pragma unroll
                for (int mt = 0; mt < 4; ++mt) {
                    f32x4 ac = (mt == 0) ? a0 : (mt == 1) ? a1 : (mt == 2) ? a2 : a3;
#pragma unroll
                    for (int r = 0; r < 4; ++r) {
                        int gr = mt * 16 + lk * 4 + r;
                        if (gr < LL) R1[gr * 196 + ncol] = ac[r] + bia;
                    }
                }
            } else if (out == 1) {
#pragma unroll
                for (int mt = 0; mt < 4; ++mt) {
                    f32x4 ac = (mt == 0) ? a0 : (mt == 1) ? a1 : (mt == 2) ? a2 : a3;
#pragma unroll
                    for (int r = 0; r < 4; ++r) {
                        int gr = mt * 16 + lk * 4 + r;
                        if (gr < LL) R2[gr * 196 + ncol] = ac[r];
                    }
                }
            } else {
                float bia = wg1b[ncol] + GLs[ncol];
                float gqv = gq[ncol];
#pragma unroll
                for (int mt = 0; mt < 4; ++mt) {
                    f32x4 ac = (mt == 0) ? a0 : (mt == 1) ? a1 : (mt == 2) ? a2 : a3;
                    int gr0 = mt * 16 + lk * 4;
                    float v0 = ac[0] + bia, v1 = ac[1] + bia, v2 = ac[2] + bia, v3 = ac[3] + bia;
                    float c0 = (gr0 + 0 < LL) ? gqv / (1.f + expf(-v0)) : 0.f;
                    float c1 = (gr0 + 1 < LL) ? gqv / (1.f + expf(-v1)) : 0.f;
                    float c2 = (gr0 + 2 < LL) ? gqv / (1.f + expf(-v2)) : 0.f;
                    float c3 = (gr0 + 3 < LL) ? gqv / (1.f + expf(-v3)) : 0.f;
#pragma unroll
                    for (int off = 1; off < 16; off <<= 1) {
                        c0 += __shfl_xor(c0, off); c1 += __shfl_xor(c1, off);
                        c2 += __shfl_xor(c2, off); c3 += __shfl_xor(c3, off);
                    }
                    if (lr == 0) {
                        if (gr0 + 0 < LL) atomicAdd(&ags[gr0 + 0], c0);
                        if (gr0 + 1 < LL) atomicAdd(&ags[gr0 + 1], c1);
                        if (gr0 + 2 < LL) atomicAdd(&ags[gr0 + 2], c2);
                        if (gr0 + 3 < LL) atomicAdd(&ags[gr0 + 3], c3);
                    }
                }
            }
        }
    }
    __syncthreads();

    // ---- P2: alpha + masked softmax -> Ab16 (wave pairs split i-rows) ----
    {
        const int d0 = (wv & 7) * 24;
        const int ih = wv >> 3;
        float kr[24], wr[24];
        {
            const float* wp = vw0 + d0;
#pragma unroll
            for (int q = 0; q < 6; ++q) {
                float4 v = *(const float4*)(wp + q * 4);
                wr[q * 4] = v.x; wr[q * 4 + 1] = v.y; wr[q * 4 + 2] = v.z; wr[q * 4 + 3] = v.w;
            }
            if (l < LL) {
                const float* kp = R1 + l * 196 + d0;
#pragma unroll
                for (int q = 0; q < 6; ++q) {
                    float4 v = *(const float4*)(kp + q * 4);
                    kr[q * 4] = v.x; kr[q * 4 + 1] = v.y; kr[q * 4 + 2] = v.z; kr[q * 4 + 3] = v.w;
                }
            } else {
#pragma unroll
                for (int q = 0; q < 24; ++q) kr[q] = 0.f;
            }
        }
        __syncthreads();   // kr cached; R1 free -> parts
        float* parts = R1;              // [8][12][64]
        const float NEG = -__builtin_inff();
        bool valid = (l < LL) && (msk[l] != 0);
        for (int i0 = 0; i0 < LL; i0 += 12) {
            int cnt = (i0 + 12 <= LL) ? 12 : (LL - i0);
            for (int i = ih; i < cnt; i += 2) {
                const float* qrow = R2 + (i0 + i) * 196 + d0;
                float b0 = 0, b1 = 0, b2 = 0, b3 = 0;
#pragma unroll
                for (int q = 0; q < 6; ++q) {
                    float4 qv = *(const float4*)(qrow + q * 4);
                    b0 += fmaxf(kr[q * 4 + 0] + qv.x, 0.f) * wr[q * 4 + 0];
                    b1 += fmaxf(kr[q * 4 + 1] + qv.y, 0.f) * wr[q * 4 + 1];
                    b2 += fmaxf(kr[q * 4 + 2] + qv.z, 0.f) * wr[q * 4 + 2];
                    b3 += fmaxf(kr[q * 4 + 3] + qv.w, 0.f) * wr[q * 4 + 3];
                }
                parts[((wv & 7) * 12 + i) * 64 + l] = (b0 + b1) + (b2 + b3);
            }
            __syncthreads();
            for (int i = wv; i < cnt; i += 16) {
                float aj = 0.f;
#pragma unroll
                for (int w2 = 0; w2 < 8; ++w2) aj += parts[(w2 * 12 + i) * 64 + l];
                if (!valid) aj = NEG;
                float m = aj;
#pragma unroll
                for (int off = 32; off; off >>= 1) m = fmaxf(m, __shfl_xor(m, off));
                float e = valid ? expf(aj - m) : 0.f;
                float s = e;
#pragma unroll
                for (int off = 32; off; off >>= 1) s += __shfl_xor(s, off);
                Ab16[(i0 + i) * 72 + l] = f2bf(e / s);   // 0 for l>=LL
            }
            __syncthreads();
        }
    }

    // ---- P3: S = Ab @ X via MFMA (A=Ab16, B=X16T) -> R2 f32 + Bs16 bf16 ----
    for (int task = wv; task < 48; task += 16) {
        int mt = task / 12, nt = task - (task / 12) * 12;
        int i0 = mt * 16, d0c = nt * 16;
        short8 aA0 = *(const short8*)(Ab16 + (i0 + lr) * 72 + lk * 8);
        short8 aA1 = *(const short8*)(Ab16 + (i0 + lr) * 72 + 32 + lk * 8);
        short8 bB0 = *(const short8*)(X16T + (d0c + lr) * 72 + lk * 8);
        short8 bB1 = *(const short8*)(X16T + (d0c + lr) * 72 + 32 + lk * 8);
        f32x4 ac = {};
        ac = __builtin_amdgcn_mfma_f32_16x16x32_bf16(aA0, bB0, ac, 0, 0, 0);
        ac = __builtin_amdgcn_mfma_f32_16x16x32_bf16(aA1, bB1, ac, 0, 0, 0);
        int d = d0c + lr;
#pragma unroll
        for (int r = 0; r < 4; ++r) {
            int i = i0 + lk * 4 + r;
            if (i < LL) {
                R2[i * 196 + d] = ac[r];
                int byte = (i * 384 + d * 2) ^ ((i & 7) << 4);
                *(unsigned short*)((char*)Bs16 + byte) = f2bf(ac[r]);
            }
        }
    }
    __syncthreads();

    // ---- P4: H2 = relu(S@w1 + b) -> Bs16 (one ncol-tile per wave, 12 waves) ----
    {
        short8 sfr[4][6];
        f32x4 h0[4] = {};
        if (wv < 12) {
#pragma unroll
            for (int mt = 0; mt < 4; ++mt) {
                int row = mt * 16 + lr;
#pragma unroll
                for (int ks = 0; ks < 6; ++ks) {
                    int byte = (row * 384 + (lk * 8 + ks * 32) * 2) ^ ((row & 7) << 4);
                    sfr[mt][ks] = *(const short8*)((const char*)Bs16 + byte);
                }
            }
            int ncol = wv * 16 + lr;
            const unsigned short* bp = W16 + (size_t)2 * WMAT + (size_t)ncol * DIM + lk * 8;
#pragma unroll
            for (int ks = 0; ks < 6; ++ks) {
                short8 bf = *(const short8*)(bp + ks * 32);
                h0[0] = __builtin_amdgcn_mfma_f32_16x16x32_bf16(sfr[0][ks], bf, h0[0], 0, 0, 0);
                h0[1] = __builtin_amdgcn_mfma_f32_16x16x32_bf16(sfr[1][ks], bf, h0[1], 0, 0, 0);
                h0[2] = __builtin_amdgcn_mfma_f32_16x16x32_bf16(sfr[2][ks], bf, h0[2], 0, 0, 0);
                h0[3] = __builtin_amdgcn_mfma_f32_16x16x32_bf16(sfr[3][ks], bf, h0[3], 0, 0, 0);
            }
        }
        __syncthreads();   // all S16 reads done
        if (wv < 12) {
            int gc = wv * 16 + lr;
            float bia = w1b[gc];
#pragma unroll
            for (int mt = 0; mt < 4; ++mt)
#pragma unroll
                for (int r = 0; r < 4; ++r) {
                    int gr = mt * 16 + lk * 4 + r;
                    if (gr < LL) {
                        float v = fmaxf(h0[mt][r] + bia, 0.f);
                        int byte = (gr * 384 + gc * 2) ^ ((gr & 7) << 4);
                        *(unsigned short*)((char*)Bs16 + byte) = f2bf(v);
                    }
                }
        }
    }
    __syncthreads();

    // ---- P5: S2 = H2@w2 + b + S (residual in-place in R2; one ncol-tile per wave) ----
    if (wv < 12) {
        short8 hfr[4][6];
#pragma unroll
        for (int mt = 0; mt < 4; ++mt) {
            int row = mt * 16 + lr;
#pragma unroll
            for (int ks = 0; ks < 6; ++ks) {
                int byte = (row * 384 + (lk * 8 + ks * 32) * 2) ^ ((row & 7) << 4);
                hfr[mt][ks] = *(const short8*)((const char*)Bs16 + byte);
            }
        }
        int ncol = wv * 16 + lr;
        const unsigned short* bp = W16 + (size_t)3 * WMAT + (size_t)ncol * DIM + lk * 8;
        f32x4 s0 = {}, s1 = {}, s2 = {}, s3 = {};
#pragma unroll
        for (int ks = 0; ks < 6; ++ks) {
            short8 bf = *(const short8*)(bp + ks * 32);
            s0 = __builtin_amdgcn_mfma_f32_16x16x32_bf16(hfr[0][ks], bf, s0, 0, 0, 0);
            s1 = __builtin_amdgcn_mfma_f32_16x16x32_bf16(hfr[1][ks], bf, s1, 0, 0, 0);
            s2 = __builtin_amdgcn_mfma_f32_16x16x32_bf16(hfr[2][ks], bf, s2, 0, 0, 0);
            s3 = __builtin_amdgcn_mfma_f32_16x16x32_bf16(hfr[3][ks], bf, s3, 0, 0, 0);
        }
        float bia = w2b[ncol];
#pragma unroll
        for (int mt = 0; mt < 4; ++mt) {
            f32x4 ac = (mt == 0) ? s0 : (mt == 1) ? s1 : (mt == 2) ? s2 : s3;
#pragma unroll
            for (int r = 0; r < 4; ++r) {
                int gr = mt * 16 + lk * 4 + r;
                if (gr < LL) R2[gr * 196 + ncol] = ac[r] + bia + R2[gr * 196 + ncol];
            }
        }
    }
    __syncthreads();

    // ---- P6: LayerNorm rows of R2 in place ----
    for (int r = wv; r < LL; r += 16) {
        float* p = R2 + r * 196;
        float v0 = p[l], v1 = p[l + 64], v2 = p[l + 128];
        float s = v0 + v1 + v2;
#pragma unroll
        for (int off = 32; off; off >>= 1) s += __shfl_xor(s, off);
        float mu = s * (1.f / DIM);
        float d0 = v0 - mu, d1 = v1 - mu, d2 = v2 - mu;
        float q = d0 * d0 + d1 * d1 + d2 * d2;
#pragma unroll
        for (int off = 32; off; off >>= 1) q += __shfl_xor(q, off);
        float inv = rsqrtf(q * (1.f / DIM) + EPS);
        p[l]       = lng[l] * d0 * inv + lnb[l];
        p[l + 64]  = lng[l + 64] * d1 * inv + lnb[l + 64];
        p[l + 128] = lng[l + 128] * d2 * inv + lnb[l + 128];
    }
    __syncthreads();

    // ---- P7: cvec = [ST, sl, SG], split 25-row halves across 4 thread groups ----
    if (t < DIM) {
        float st = 0.f;
        for (int p = 0; p < 25; ++p) st += was[p] * R2[p * 196 + t];
        cvec[t] = st;
        cvec[DIM + t] = xlast[t];
    } else if (t >= 256 && t < 256 + DIM) {
        int d = t - 256;
        float st = 0.f;
        for (int p = 25; p < LL; ++p) st += was[p] * R2[p * 196 + d];
        stB[d] = st;
    } else if (t >= 512 && t < 512 + DIM) {
        int d = t - 512;
        float sg = 0.f;
        const unsigned short* xr = X16T + d * 72;
        for (int p = 0; p < 25; ++p) sg += ags[p] * bf2f(xr[p]);
        cvec[2 * DIM + d] = sg;
    } else if (t >= 768 && t < 768 + DIM) {
        int d = t - 768;
        float sg = 0.f;
        const unsigned short* xr = X16T + d * 72;
        for (int p = 25; p < LL; ++p) sg += ags[p] * bf2f(xr[p]);
        sgB[d] = sg;
    }
    __syncthreads();
    if (t < DIM) {
        cvec[t] += stB[t];
        cvec[2 * DIM + t] += sgB[t];
    }
    __syncthreads();

    // ---- P8: c = normalize(selu(cvec @ wf^T + wf_b)) -> Cb16 global (8-way split) ----
    {
        int out = t & 127, part = t >> 7;
        float s = (part == 0) ? wfb[out] : 0.f;
        const float* wr = wfW + (size_t)out * (3 * DIM) + part * 72;
        const float* cv = cvec + part * 72;
        for (int e = 0; e < 72; e += 4) {
            float4 w4 = *(const float4*)(wr + e);
            s += cv[e] * w4.x + cv[e + 1] * w4.y + cv[e + 2] * w4.z + cv[e + 3] * w4.w;
        }
        red2[part][out] = s;
    }
    __syncthreads();
    float cj = 0.f;
    if (t < IDIM) {
        float s = red2[0][t] + red2[1][t] + red2[2][t] + red2[3][t]
                + red2[4][t] + red2[5][t] + red2[6][t] + red2[7][t];
        const float sa = 1.6732632423543772f, sc = 1.0507009873554805f;
        cj = sc * (s > 0.f ? s : sa * expm1f(s));
    }
    float sq = cj * cj;
#pragma unroll
    for (int off = 32; off; off >>= 1) sq += __shfl_xor(sq, off);
    if (l == 0 && wv < 2) red[wv] = sq;
    __syncthreads();
    if (t < IDIM) {
        float nrm = sqrtf(red[0] + red[1]);
        Cb16g[b * IDIM + t] = f2bf(cj / nrm);
    }
}

// ---------------- Z: block = 64n strip x full 256m, LDS-transposed coalesced stores ----------------
__global__ __launch_bounds__(256) void k_z4(const unsigned short* __restrict__ Cb16,
                                            const unsigned short* __restrict__ emb16,
                                            const float* __restrict__ invn,
                                            float* __restrict__ Z) {
    __shared__ float tr[4][64][68];
    int n0 = blockIdx.x * 64;
    int t = threadIdx.x, w = t >> 6, l = t & 63;
    int lr = l & 15, lk = l >> 4;

    short8 a[4][4];
#pragma unroll
    for (int mt = 0; mt < 4; ++mt) {
        int mrow = w * 64 + mt * 16 + lr;
        const unsigned short* ap = Cb16 + (size_t)mrow * IDIM + lk * 8;
#pragma unroll
        for (int ks = 0; ks < 4; ++ks) a[mt][ks] = *(const short8*)(ap + ks * 32);
    }
    f32x4 acc[4][4] = {};
#pragma unroll
    for (int nt = 0; nt < 4; ++nt) {
        int nrow = n0 + nt * 16 + lr;
        short8 bfr[4];
        if (nrow < NOUT) {
            const unsigned short* bp = emb16 + (size_t)(nrow + 1) * IDIM + lk * 8;
#pragma unroll
            for (int ks = 0; ks < 4; ++ks) bfr[ks] = *(const short8*)(bp + ks * 32);
        } else {
            short8 z = {};
#pragma unroll
            for (int ks = 0; ks < 4; ++ks) bfr[ks] = z;
        }
#pragma unroll
        for (int mt = 0; mt < 4; ++mt)
#pragma unroll
            for (int ks = 0; ks < 4; ++ks)
                acc[mt][nt] = __builtin_amdgcn_mfma_f32_16x16x32_bf16(a[mt][ks], bfr[ks], acc[mt][nt], 0, 0, 0);
    }
#pragma unroll
    for (int nt = 0; nt < 4; ++nt) {
        int gn = n0 + nt * 16 + lr;
        float sc = (gn < NOUT) ? WSC * invn[gn + 1] : 0.f;
#pragma unroll
        for (int mt = 0; mt < 4; ++mt)
#pragma unroll
            for (int r = 0; r < 4; ++r)
                tr[w][mt * 16 + lk * 4 + r][nt * 16 + lr] = acc[mt][nt][r] * sc;
    }
    __syncthreads();
    int q = l >> 4, s = l & 15;
    bool tail = (n0 + 64) > NOUT;
#pragma unroll
    for (int it = 0; it < 16; ++it) {
        int row = it * 4 + q;
        int gm  = w * 64 + row;
        float4 v = *(const float4*)&tr[w][row][s * 4];
        if (!tail) {
            *(float4*)&Z[(size_t)gm * NOUT + n0 + s * 4] = v;
        } else {
            int c0 = n0 + s * 4;
            float vv[4] = {v.x, v.y, v.z, v.w};
#pragma unroll
            for (int j = 0; j < 4; ++j)
                if (c0 + j < NOUT) Z[(size_t)gm * NOUT + c0 + j] = vv[j];
        }
    }
}

extern "C" void kernel_launch(void* const* d_in, const int* in_sizes, int n_in,
                              void* d_out, int out_size, void* d_ws, size_t ws_size,
                              hipStream_t stream) {
    const int*   x     = (const int*)d_in[0];
    const int*   pos   = (const int*)d_in[1];
    const float* emb   = (const float*)d_in[2];
    const float* pose  = (const float*)d_in[3];
    const float* vw0   = (const float*)d_in[4];
    const float* vw1   = (const float*)d_in[5];
    const float* vw2   = (const float*)d_in[6];
    const float* vbias = (const float*)d_in[7];
    const float* w1W   = (const float*)d_in[8];
    const float* w1b   = (const float*)d_in[9];
    const float* w2W   = (const float*)d_in[10];
    const float* w2b   = (const float*)d_in[11];
    const float* wA    = (const float*)d_in[12];
    const float* wg1W  = (const float*)d_in[13];
    const float* wg1b  = (const float*)d_in[14];
    const float* wg2W  = (const float*)d_in[15];
    const float* wg2b  = (const float*)d_in[16];
    const float* gq    = (const float*)d_in[17];
    const float* wfW   = (const float*)d_in[18];
    const float* wfb   = (const float*)d_in[19];
    const float* lng   = (const float*)d_in[20];
    const float* lnb   = (const float*)d_in[21];
    float* Z = (float*)d_out;

    float* w = (float*)d_ws;
    float* scale  = w; w += NITEMS;
    float* invn   = w; w += NITEMS;
    float* pscale = w; w += 64;
    w = (float*)(((uintptr_t)w + 15) & ~(uintptr_t)15);
    unsigned short* emb16 = (unsigned short*)w; w += (size_t)NITEMS * IDIM / 2;
    unsigned short* W16   = (unsigned short*)w; w += (size_t)5 * WMAT / 2;
    unsigned short* Cb16  = (unsigned short*)w; w += (size_t)BB * IDIM / 2;

    k_norms<<<NITEMS / 4, 256, 0, stream>>>(emb, scale, invn, emb16);
    k_pnorms<<<1, 64, 0, stream>>>(pose, pscale);
    k_cvtw<<<5 * 144, 256, 0, stream>>>(vw1, vw2, w1W, w2W, wg1W, W16);
    k_mega<<<BB, 1024, 0, stream>>>(x, pos, emb, pose, scale, pscale, W16,
                                    vw0, vbias, w1b, w2b, wg1b, wg2W, wg2b, gq,
                                    wA, lng, lnb, wfW, wfb, Cb16);
    k_z4<<<(NOUT + 63) / 64, 256, 0, stream>>>(Cb16, emb16, invn, Z);
}

// Round 15
// 128.956 us; speedup vs baseline: 1.2574x; 1.2574x over previous
//
#include <hip/hip_runtime.h>
#include <hip/hip_bf16.h>
#include <math.h>
#include <stdint.h>

#define BB 256
#define LL 50
#define IDIM 128
#define PDIM 64
#define DIM 192
#define NITEMS 50000
#define NOUT 49999
#define WSC 20.0f
#define EPS 1e-5f
#define WMAT (DIM * DIM)

typedef __attribute__((ext_vector_type(8))) short  short8;
typedef __attribute__((ext_vector_type(4))) float  f32x4;

__device__ __forceinline__ unsigned short f2bf(float f) {
    unsigned int u = __float_as_uint(f);
    u = (u + 0x7FFFu + ((u >> 16) & 1u)) >> 16;
    return (unsigned short)u;
}
__device__ __forceinline__ float bf2f(unsigned short u) {
    unsigned int v = ((unsigned int)u) << 16;
    return __uint_as_float(v);
}

// ---------------- row norms of emb + bf16 copy ----------------
__global__ __launch_bounds__(256) void k_norms(const float* __restrict__ emb,
                                               float* __restrict__ scale,
                                               float* __restrict__ invn,
                                               unsigned short* __restrict__ emb16) {
    int row  = blockIdx.x * 4 + (threadIdx.x >> 6);
    int lane = threadIdx.x & 63;
    const float* p = emb + (size_t)row * IDIM;
    float a = p[lane], b = p[lane + 64];
    emb16[(size_t)row * IDIM + lane]      = f2bf(a);
    emb16[(size_t)row * IDIM + lane + 64] = f2bf(b);
    float s = a * a + b * b;
#pragma unroll
    for (int off = 32; off; off >>= 1) s += __shfl_xor(s, off);
    if (lane == 0) {
        float n = sqrtf(s);
        scale[row] = fminf(1.0f, 1.5f / fmaxf(n, 1e-7f));
        invn[row]  = (n > 0.f) ? 1.f / n : 0.f;
    }
}

__global__ __launch_bounds__(64) void k_pnorms(const float* __restrict__ pe,
                                               float* __restrict__ pscale) {
    int row = threadIdx.x;
    if (row > LL) return;
    float s = 0.f;
    const float* p = pe + row * PDIM;
    for (int d = 0; d < PDIM; ++d) { float v = p[d]; s += v * v; }
    float n = sqrtf(s);
    pscale[row] = fminf(1.0f, 1.5f / fmaxf(n, 1e-7f));
}

// ---------------- weight convert (+transpose for vw1,vw2) ----------------
// W16 layout: [0]=vw1^T [1]=vw2^T [2]=w1W [3]=w2W [4]=wg1W, each [n][k] 192x192
__global__ __launch_bounds__(256) void k_cvtw(const float* __restrict__ vw1, const float* __restrict__ vw2,
                                              const float* __restrict__ w1W, const float* __restrict__ w2W,
                                              const float* __restrict__ wg1W,
                                              unsigned short* __restrict__ Wout) {
    int b = blockIdx.x;
    int wi = b / 144;
    int pos = (b % 144) * 256 + threadIdx.x;
    int n = pos / DIM, k = pos - n * DIM;
    float v;
    if      (wi == 0) v = vw1[(size_t)k * DIM + n];
    else if (wi == 1) v = vw2[(size_t)k * DIM + n];
    else if (wi == 2) v = w1W[pos];
    else if (wi == 3) v = w2W[pos];
    else              v = wg1W[pos];
    Wout[(size_t)wi * WMAT + pos] = f2bf(v);
}

// ================= MEGAKERNEL (1024 threads = 16 waves, low-register) =================
__global__ __launch_bounds__(1024) void k_mega(
    const int* __restrict__ x, const int* __restrict__ pos,
    const float* __restrict__ emb, const float* __restrict__ pe,
    const float* __restrict__ scale, const float* __restrict__ pscale,
    const unsigned short* __restrict__ W16,
    const float* __restrict__ vw0, const float* __restrict__ vbias,
    const float* __restrict__ w1b, const float* __restrict__ w2b,
    const float* __restrict__ wg1b, const float* __restrict__ wg2W,
    const float* __restrict__ wg2b, const float* __restrict__ gq,
    const float* __restrict__ wA, const float* __restrict__ lng,
    const float* __restrict__ lnb, const float* __restrict__ wfW,
    const float* __restrict__ wfb, unsigned short* __restrict__ Cb16g) {

    __shared__ unsigned short Bs16[64 * DIM];   // swizzled: X16 -> S16 -> H16
    __shared__ unsigned short X16T[DIM * 72];   // X^T bf16 [d][j], cols 50..63 zero
    __shared__ unsigned short Ab16[64 * 72];    // attn weights bf16 [i][j]
    __shared__ float R1[LL * 196];              // K' -> parts[16][6][64]
    __shared__ float R2[LL * 196];              // Q -> S -> S2/S3
    __shared__ float xlast[DIM];
    __shared__ float GLs[DIM];
    __shared__ float cvec[3 * DIM];
    __shared__ float stB[DIM], sgB[DIM];
    __shared__ float red2[8][128];
    __shared__ float ags[64];
    __shared__ int   msk[64];
    __shared__ float was[64];
    __shared__ float red[16];
    __shared__ int   xi[LL], pii[LL];
    __shared__ float xsc[LL], psc[LL];

    const int b = blockIdx.x, t = threadIdx.x;
    const int wv = t >> 6, l = t & 63;
    const int lr = l & 15, lk = l >> 4;

    // ---- P0: indices, consts ----
    if (t < LL) {
        int v = x[b * LL + t];  xi[t] = v;  xsc[t] = scale[v];
        int pv = pos[b * LL + t]; pii[t] = pv; psc[t] = pscale[pv];
    }
    if (t >= 64 && t < 128) ags[t - 64] = 0.f;
    if (t >= 128 && t < 128 + LL) was[t - 128] = wA[t - 128];
    __syncthreads();
    if (t < 64) msk[t] = (t < LL) ? xi[t] : 0;
    // gather: wave per row, lane = d
    for (int r = wv; r < LL; r += 16) {
        float sx = xsc[r], sp = psc[r];
        float v0 = emb[(size_t)xi[r] * IDIM + l] * sx;
        float v1 = emb[(size_t)xi[r] * IDIM + l + 64] * sx;
        float v2 = pe[pii[r] * PDIM + l] * sp;
        int base = r * 384, sw = (r & 7) << 4;
        *(unsigned short*)((char*)Bs16 + ((base + l * 2) ^ sw))         = f2bf(v0);
        *(unsigned short*)((char*)Bs16 + ((base + (l + 64) * 2) ^ sw))  = f2bf(v1);
        *(unsigned short*)((char*)Bs16 + ((base + (l + 128) * 2) ^ sw)) = f2bf(v2);
        X16T[l * 72 + r]         = f2bf(v0);
        X16T[(l + 64) * 72 + r]  = f2bf(v1);
        X16T[(l + 128) * 72 + r] = f2bf(v2);
        if (r == 49) { xlast[l] = v0; xlast[l + 64] = v1; xlast[l + 128] = v2; }
    }
    // zero pads: Bs16 rows 50-63, X16T cols 50-63, Ab16 rows 50-63
    for (int e = t; e < 14 * DIM; e += 1024) Bs16[LL * DIM + e] = 0;
    for (int e = t; e < DIM * 14; e += 1024) { int d = e / 14, j = 50 + (e - d * 14); X16T[d * 72 + j] = 0; }
    for (int e = t; e < 14 * 72; e += 1024) Ab16[50 * 72 + e] = 0;
    __syncthreads();

    // ---- GL = xlast @ wg2W^T + wg2b ----
    if (t < DIM) {
        float g = wg2b[t];
        const float* wr = wg2W + (size_t)t * DIM;
        float s0 = 0, s1 = 0, s2 = 0, s3 = 0;
        for (int k = 0; k < DIM; k += 4) {
            float4 w4 = *(const float4*)(wr + k);
            s0 += xlast[k] * w4.x; s1 += xlast[k + 1] * w4.y;
            s2 += xlast[k + 2] * w4.z; s3 += xlast[k + 3] * w4.w;
        }
        GLs[t] = g + ((s0 + s1) + (s2 + s3));
    }
    __syncthreads();

    // ---- P1: three GEMMs, per-mt streaming (low reg): K'->R1, Q->R2, Gpre->ags ----
    for (int task = wv; task < 36; task += 16) {
        int out = task / 12, nt = task % 12;
        int ncol = nt * 16 + lr;
        const unsigned short* bp = W16 + (size_t)(out == 0 ? 0 : (out == 1 ? 1 : 4)) * WMAT
                                   + (size_t)ncol * DIM + lk * 8;
#pragma unroll
        for (int mt = 0; mt < 4; ++mt) {
            int row = mt * 16 + lr;
            f32x4 ac = {};
#pragma unroll
            for (int ks = 0; ks < 6; ++ks) {
                int byte = (row * 384 + (lk * 8 + ks * 32) * 2) ^ ((row & 7) << 4);
                short8 af = *(const short8*)((const char*)Bs16 + byte);
                short8 bf = *(const short8*)(bp + ks * 32);
                ac = __builtin_amdgcn_mfma_f32_16x16x32_bf16(af, bf, ac, 0, 0, 0);
            }
            if (out == 0) {
                float bia = vbias[ncol];
#pragma unroll
                for (int r = 0; r < 4; ++r) {
                    int gr = mt * 16 + lk * 4 + r;
                    if (gr < LL) R1[gr * 196 + ncol] = ac[r] + bia;
                }
            } else if (out == 1) {
#pragma unroll
                for (int r = 0; r < 4; ++r) {
                    int gr = mt * 16 + lk * 4 + r;
                    if (gr < LL) R2[gr * 196 + ncol] = ac[r];
                }
            } else {
                float bia = wg1b[ncol] + GLs[ncol];
                float gqv = gq[ncol];
                int gr0 = mt * 16 + lk * 4;
                float v0 = ac[0] + bia, v1 = ac[1] + bia, v2 = ac[2] + bia, v3 = ac[3] + bia;
                float c0 = (gr0 + 0 < LL) ? gqv / (1.f + expf(-v0)) : 0.f;
                float c1 = (gr0 + 1 < LL) ? gqv / (1.f + expf(-v1)) : 0.f;
                float c2 = (gr0 + 2 < LL) ? gqv / (1.f + expf(-v2)) : 0.f;
                float c3 = (gr0 + 3 < LL) ? gqv / (1.f + expf(-v3)) : 0.f;
#pragma unroll
                for (int off = 1; off < 16; off <<= 1) {
                    c0 += __shfl_xor(c0, off); c1 += __shfl_xor(c1, off);
                    c2 += __shfl_xor(c2, off); c3 += __shfl_xor(c3, off);
                }
                if (lr == 0) {
                    if (gr0 + 0 < LL) atomicAdd(&ags[gr0 + 0], c0);
                    if (gr0 + 1 < LL) atomicAdd(&ags[gr0 + 1], c1);
                    if (gr0 + 2 < LL) atomicAdd(&ags[gr0 + 2], c2);
                    if (gr0 + 3 < LL) atomicAdd(&ags[gr0 + 3], c3);
                }
            }
        }
    }
    __syncthreads();

    // ---- P2: alpha + masked softmax -> Ab16 (16 waves x 12-dim slices) ----
    {
        const int d0 = wv * 12;
        float kr[12], wr[12];
        {
            const float* wp = vw0 + d0;
#pragma unroll
            for (int q = 0; q < 3; ++q) {
                float4 v = *(const float4*)(wp + q * 4);
                wr[q * 4] = v.x; wr[q * 4 + 1] = v.y; wr[q * 4 + 2] = v.z; wr[q * 4 + 3] = v.w;
            }
            if (l < LL) {
                const float* kp = R1 + l * 196 + d0;
#pragma unroll
                for (int q = 0; q < 3; ++q) {
                    float4 v = *(const float4*)(kp + q * 4);
                    kr[q * 4] = v.x; kr[q * 4 + 1] = v.y; kr[q * 4 + 2] = v.z; kr[q * 4 + 3] = v.w;
                }
            } else {
#pragma unroll
                for (int q = 0; q < 12; ++q) kr[q] = 0.f;
            }
        }
        __syncthreads();   // kr cached; R1 free -> parts
        float* parts = R1;              // [16][6][64] = 6144 floats
        const float NEG = -__builtin_inff();
        bool valid = (l < LL) && (msk[l] != 0);
        for (int i0 = 0; i0 < LL; i0 += 6) {
            int cnt = (i0 + 6 <= LL) ? 6 : (LL - i0);
            for (int i = 0; i < cnt; ++i) {
                const float* qrow = R2 + (i0 + i) * 196 + d0;
                float b0 = 0, b1 = 0, b2 = 0, b3 = 0;
#pragma unroll
                for (int q = 0; q < 3; ++q) {
                    float4 qv = *(const float4*)(qrow + q * 4);
                    b0 += fmaxf(kr[q * 4 + 0] + qv.x, 0.f) * wr[q * 4 + 0];
                    b1 += fmaxf(kr[q * 4 + 1] + qv.y, 0.f) * wr[q * 4 + 1];
                    b2 += fmaxf(kr[q * 4 + 2] + qv.z, 0.f) * wr[q * 4 + 2];
                    b3 += fmaxf(kr[q * 4 + 3] + qv.w, 0.f) * wr[q * 4 + 3];
                }
                parts[(wv * 6 + i) * 64 + l] = (b0 + b1) + (b2 + b3);
            }
            __syncthreads();
            for (int i = wv; i < cnt; i += 16) {
                float aj = 0.f;
#pragma unroll
                for (int w2 = 0; w2 < 16; ++w2) aj += parts[(w2 * 6 + i) * 64 + l];
                if (!valid) aj = NEG;
                float m = aj;
#pragma unroll
                for (int off = 32; off; off >>= 1) m = fmaxf(m, __shfl_xor(m, off));
                float e = valid ? expf(aj - m) : 0.f;
                float s = e;
#pragma unroll
                for (int off = 32; off; off >>= 1) s += __shfl_xor(s, off);
                Ab16[(i0 + i) * 72 + l] = f2bf(e / s);   // 0 for l>=LL
            }
            __syncthreads();
        }
    }

    // ---- P3: S = Ab @ X via MFMA (A=Ab16, B=X16T) -> R2 f32 + Bs16 bf16 ----
    for (int task = wv; task < 48; task += 16) {
        int mt = task / 12, nt = task - (task / 12) * 12;
        int i0 = mt * 16, d0c = nt * 16;
        short8 aA0 = *(const short8*)(Ab16 + (i0 + lr) * 72 + lk * 8);
        short8 aA1 = *(const short8*)(Ab16 + (i0 + lr) * 72 + 32 + lk * 8);
        short8 bB0 = *(const short8*)(X16T + (d0c + lr) * 72 + lk * 8);
        short8 bB1 = *(const short8*)(X16T + (d0c + lr) * 72 + 32 + lk * 8);
        f32x4 ac = {};
        ac = __builtin_amdgcn_mfma_f32_16x16x32_bf16(aA0, bB0, ac, 0, 0, 0);
        ac = __builtin_amdgcn_mfma_f32_16x16x32_bf16(aA1, bB1, ac, 0, 0, 0);
        int d = d0c + lr;
#pragma unroll
        for (int r = 0; r < 4; ++r) {
            int i = i0 + lk * 4 + r;
            if (i < LL) {
                R2[i * 196 + d] = ac[r];
                int byte = (i * 384 + d * 2) ^ ((i & 7) << 4);
                *(unsigned short*)((char*)Bs16 + byte) = f2bf(ac[r]);
            }
        }
    }
    __syncthreads();

    // ---- P4: H2 = relu(S@w1 + b) -> Bs16 (per-mt streaming, 12 waves) ----
    {
        f32x4 h[4] = {};
        if (wv < 12) {
            int ncol = wv * 16 + lr;
            const unsigned short* bp = W16 + (size_t)2 * WMAT + (size_t)ncol * DIM + lk * 8;
#pragma unroll
            for (int mt = 0; mt < 4; ++mt) {
                int row = mt * 16 + lr;
#pragma unroll
                for (int ks = 0; ks < 6; ++ks) {
                    int byte = (row * 384 + (lk * 8 + ks * 32) * 2) ^ ((row & 7) << 4);
                    short8 sf = *(const short8*)((const char*)Bs16 + byte);
                    short8 bf = *(const short8*)(bp + ks * 32);
                    h[mt] = __builtin_amdgcn_mfma_f32_16x16x32_bf16(sf, bf, h[mt], 0, 0, 0);
                }
            }
        }
        __syncthreads();   // all S16 reads done
        if (wv < 12) {
            int gc = wv * 16 + lr;
            float bia = w1b[gc];
#pragma unroll
            for (int mt = 0; mt < 4; ++mt)
#pragma unroll
                for (int r = 0; r < 4; ++r) {
                    int gr = mt * 16 + lk * 4 + r;
                    if (gr < LL) {
                        float v = fmaxf(h[mt][r] + bia, 0.f);
                        int byte = (gr * 384 + gc * 2) ^ ((gr & 7) << 4);
                        *(unsigned short*)((char*)Bs16 + byte) = f2bf(v);
                    }
                }
        }
    }
    __syncthreads();

    // ---- P5: S2 = H2@w2 + b + S (residual in-place in R2; per-mt streaming) ----
    if (wv < 12) {
        int ncol = wv * 16 + lr;
        const unsigned short* bp = W16 + (size_t)3 * WMAT + (size_t)ncol * DIM + lk * 8;
        float bia = w2b[ncol];
#pragma unroll
        for (int mt = 0; mt < 4; ++mt) {
            int row = mt * 16 + lr;
            f32x4 ac = {};
#pragma unroll
            for (int ks = 0; ks < 6; ++ks) {
                int byte = (row * 384 + (lk * 8 + ks * 32) * 2) ^ ((row & 7) << 4);
                short8 hf = *(const short8*)((const char*)Bs16 + byte);
                short8 bf = *(const short8*)(bp + ks * 32);
                ac = __builtin_amdgcn_mfma_f32_16x16x32_bf16(hf, bf, ac, 0, 0, 0);
            }
#pragma unroll
            for (int r = 0; r < 4; ++r) {
                int gr = mt * 16 + lk * 4 + r;
                if (gr < LL) R2[gr * 196 + ncol] = ac[r] + bia + R2[gr * 196 + ncol];
            }
        }
    }
    __syncthreads();

    // ---- P6: LayerNorm rows of R2 in place ----
    for (int r = wv; r < LL; r += 16) {
        float* p = R2 + r * 196;
        float v0 = p[l], v1 = p[l + 64], v2 = p[l + 128];
        float s = v0 + v1 + v2;
#pragma unroll
        for (int off = 32; off; off >>= 1) s += __shfl_xor(s, off);
        float mu = s * (1.f / DIM);
        float d0 = v0 - mu, d1 = v1 - mu, d2 = v2 - mu;
        float q = d0 * d0 + d1 * d1 + d2 * d2;
#pragma unroll
        for (int off = 32; off; off >>= 1) q += __shfl_xor(q, off);
        float inv = rsqrtf(q * (1.f / DIM) + EPS);
        p[l]       = lng[l] * d0 * inv + lnb[l];
        p[l + 64]  = lng[l + 64] * d1 * inv + lnb[l + 64];
        p[l + 128] = lng[l + 128] * d2 * inv + lnb[l + 128];
    }
    __syncthreads();

    // ---- P7: cvec = [ST, sl, SG], split 25-row halves across 4 thread groups ----
    if (t < DIM) {
        float st = 0.f;
        for (int p = 0; p < 25; ++p) st += was[p] * R2[p * 196 + t];
        cvec[t] = st;
        cvec[DIM + t] = xlast[t];
    } else if (t >= 256 && t < 256 + DIM) {
        int d = t - 256;
        float st = 0.f;
        for (int p = 25; p < LL; ++p) st += was[p] * R2[p * 196 + d];
        stB[d] = st;
    } else if (t >= 512 && t < 512 + DIM) {
        int d = t - 512;
        float sg = 0.f;
        const unsigned short* xr = X16T + d * 72;
        for (int p = 0; p < 25; ++p) sg += ags[p] * bf2f(xr[p]);
        cvec[2 * DIM + d] = sg;
    } else if (t >= 768 && t < 768 + DIM) {
        int d = t - 768;
        float sg = 0.f;
        const unsigned short* xr = X16T + d * 72;
        for (int p = 25; p < LL; ++p) sg += ags[p] * bf2f(xr[p]);
        sgB[d] = sg;
    }
    __syncthreads();
    if (t < DIM) {
        cvec[t] += stB[t];
        cvec[2 * DIM + t] += sgB[t];
    }
    __syncthreads();

    // ---- P8: c = normalize(selu(cvec @ wf^T + wf_b)) -> Cb16 global (8-way split) ----
    {
        int out = t & 127, part = t >> 7;
        float s = (part == 0) ? wfb[out] : 0.f;
        const float* wr = wfW + (size_t)out * (3 * DIM) + part * 72;
        const float* cv = cvec + part * 72;
        for (int e = 0; e < 72; e += 4) {
            float4 w4 = *(const float4*)(wr + e);
            s += cv[e] * w4.x + cv[e + 1] * w4.y + cv[e + 2] * w4.z + cv[e + 3] * w4.w;
        }
        red2[part][out] = s;
    }
    __syncthreads();
    float cj = 0.f;
    if (t < IDIM) {
        float s = red2[0][t] + red2[1][t] + red2[2][t] + red2[3][t]
                + red2[4][t] + red2[5][t] + red2[6][t] + red2[7][t];
        const float sa = 1.6732632423543772f, sc = 1.0507009873554805f;
        cj = sc * (s > 0.f ? s : sa * expm1f(s));
    }
    float sq = cj * cj;
#pragma unroll
    for (int off = 32; off; off >>= 1) sq += __shfl_xor(sq, off);
    if (l == 0 && wv < 2) red[wv] = sq;
    __syncthreads();
    if (t < IDIM) {
        float nrm = sqrtf(red[0] + red[1]);
        Cb16g[b * IDIM + t] = f2bf(cj / nrm);
    }
}

// ---------------- Z: block = 64n strip x full 256m, LDS-transposed coalesced stores ----------------
__global__ __launch_bounds__(256) void k_z4(const unsigned short* __restrict__ Cb16,
                                            const unsigned short* __restrict__ emb16,
                                            const float* __restrict__ invn,
                                            float* __restrict__ Z) {
    __shared__ float tr[4][64][68];
    int n0 = blockIdx.x * 64;
    int t = threadIdx.x, w = t >> 6, l = t & 63;
    int lr = l & 15, lk = l >> 4;

    short8 a[4][4];
#pragma unroll
    for (int mt = 0; mt < 4; ++mt) {
        int mrow = w * 64 + mt * 16 + lr;
        const unsigned short* ap = Cb16 + (size_t)mrow * IDIM + lk * 8;
#pragma unroll
        for (int ks = 0; ks < 4; ++ks) a[mt][ks] = *(const short8*)(ap + ks * 32);
    }
    f32x4 acc[4][4] = {};
#pragma unroll
    for (int nt = 0; nt < 4; ++nt) {
        int nrow = n0 + nt * 16 + lr;
        short8 bfr[4];
        if (nrow < NOUT) {
            const unsigned short* bp = emb16 + (size_t)(nrow + 1) * IDIM + lk * 8;
#pragma unroll
            for (int ks = 0; ks < 4; ++ks) bfr[ks] = *(const short8*)(bp + ks * 32);
        } else {
            short8 z = {};
#pragma unroll
            for (int ks = 0; ks < 4; ++ks) bfr[ks] = z;
        }
#pragma unroll
        for (int mt = 0; mt < 4; ++mt)
#pragma unroll
            for (int ks = 0; ks < 4; ++ks)
                acc[mt][nt] = __builtin_amdgcn_mfma_f32_16x16x32_bf16(a[mt][ks], bfr[ks], acc[mt][nt], 0, 0, 0);
    }
#pragma unroll
    for (int nt = 0; nt < 4; ++nt) {
        int gn = n0 + nt * 16 + lr;
        float sc = (gn < NOUT) ? WSC * invn[gn + 1] : 0.f;
#pragma unroll
        for (int mt = 0; mt < 4; ++mt)
#pragma unroll
            for (int r = 0; r < 4; ++r)
                tr[w][mt * 16 + lk * 4 + r][nt * 16 + lr] = acc[mt][nt][r] * sc;
    }
    __syncthreads();
    int q = l >> 4, s = l & 15;
    bool tail = (n0 + 64) > NOUT;
#pragma unroll
    for (int it = 0; it < 16; ++it) {
        int row = it * 4 + q;
        int gm  = w * 64 + row;
        float4 v = *(const float4*)&tr[w][row][s * 4];
        if (!tail) {
            *(float4*)&Z[(size_t)gm * NOUT + n0 + s * 4] = v;
        } else {
            int c0 = n0 + s * 4;
            float vv[4] = {v.x, v.y, v.z, v.w};
#pragma unroll
            for (int j = 0; j < 4; ++j)
                if (c0 + j < NOUT) Z[(size_t)gm * NOUT + c0 + j] = vv[j];
        }
    }
}

extern "C" void kernel_launch(void* const* d_in, const int* in_sizes, int n_in,
                              void* d_out, int out_size, void* d_ws, size_t ws_size,
                              hipStream_t stream) {
    const int*   x     = (const int*)d_in[0];
    const int*   pos   = (const int*)d_in[1];
    const float* emb   = (const float*)d_in[2];
    const float* pose  = (const float*)d_in[3];
    const float* vw0   = (const float*)d_in[4];
    const float* vw1   = (const float*)d_in[5];
    const float* vw2   = (const float*)d_in[6];
    const float* vbias = (const float*)d_in[7];
    const float* w1W   = (const float*)d_in[8];
    const float* w1b   = (const float*)d_in[9];
    const float* w2W   = (const float*)d_in[10];
    const float* w2b   = (const float*)d_in[11];
    const float* wA    = (const float*)d_in[12];
    const float* wg1W  = (const float*)d_in[13];
    const float* wg1b  = (const float*)d_in[14];
    const float* wg2W  = (const float*)d_in[15];
    const float* wg2b  = (const float*)d_in[16];
    const float* gq    = (const float*)d_in[17];
    const float* wfW   = (const float*)d_in[18];
    const float* wfb   = (const float*)d_in[19];
    const float* lng   = (const float*)d_in[20];
    const float* lnb   = (const float*)d_in[21];
    float* Z = (float*)d_out;

    float* w = (float*)d_ws;
    float* scale  = w; w += NITEMS;
    float* invn   = w; w += NITEMS;
    float* pscale = w; w += 64;
    w = (float*)(((uintptr_t)w + 15) & ~(uintptr_t)15);
    unsigned short* emb16 = (unsigned short*)w; w += (size_t)NITEMS * IDIM / 2;
    unsigned short* W16   = (unsigned short*)w; w += (size_t)5 * WMAT / 2;
    unsigned short* Cb16  = (unsigned short*)w; w += (size_t)BB * IDIM / 2;

    k_norms<<<NITEMS / 4, 256, 0, stream>>>(emb, scale, invn, emb16);
    k_pnorms<<<1, 64, 0, stream>>>(pose, pscale);
    k_cvtw<<<5 * 144, 256, 0, stream>>>(vw1, vw2, w1W, w2W, wg1W, W16);
    k_mega<<<BB, 1024, 0, stream>>>(x, pos, emb, pose, scale, pscale, W16,
                                    vw0, vbias, w1b, w2b, wg1b, wg2W, wg2b, gq,
                                    wA, lng, lnb, wfW, wfb, Cb16);
    k_z4<<<(NOUT + 63) / 64, 256, 0, stream>>>(Cb16, emb16, invn, Z);
}

// Round 16
// 101.291 us; speedup vs baseline: 1.6008x; 1.2731x over previous
//
#include <hip/hip_runtime.h>
#include <hip/hip_bf16.h>
#include <math.h>
#include <stdint.h>

#define BB 256
#define LL 50
#define IDIM 128
#define PDIM 64
#define DIM 192
#define NITEMS 50000
#define NOUT 49999
#define WSC 20.0f
#define EPS 1e-5f
#define WMAT (DIM * DIM)

typedef __attribute__((ext_vector_type(8))) short  short8;
typedef __attribute__((ext_vector_type(4))) float  f32x4;

__device__ __forceinline__ unsigned short f2bf(float f) {
    unsigned int u = __float_as_uint(f);
    u = (u + 0x7FFFu + ((u >> 16) & 1u)) >> 16;
    return (unsigned short)u;
}
__device__ __forceinline__ float bf2f(unsigned short u) {
    unsigned int v = ((unsigned int)u) << 16;
    return __uint_as_float(v);
}

// ---------------- fused prep: emb norms+bf16 | weight cvt | pos norms ----------------
// blocks [0,12500): norms 4 rows each; [12500,13220): cvtw; 13220: pnorms
__global__ __launch_bounds__(256) void k_prep(const float* __restrict__ emb,
                                              float* __restrict__ scale,
                                              float* __restrict__ invn,
                                              unsigned short* __restrict__ emb16,
                                              const float* __restrict__ pe,
                                              float* __restrict__ pscale,
                                              const float* __restrict__ vw1, const float* __restrict__ vw2,
                                              const float* __restrict__ w1W, const float* __restrict__ w2W,
                                              const float* __restrict__ wg1W,
                                              unsigned short* __restrict__ Wout) {
    int blk = blockIdx.x;
    if (blk < 12500) {
        int row  = blk * 4 + (threadIdx.x >> 6);
        int lane = threadIdx.x & 63;
        const float* p = emb + (size_t)row * IDIM;
        float a = p[lane], b = p[lane + 64];
        emb16[(size_t)row * IDIM + lane]      = f2bf(a);
        emb16[(size_t)row * IDIM + lane + 64] = f2bf(b);
        float s = a * a + b * b;
#pragma unroll
        for (int off = 32; off; off >>= 1) s += __shfl_xor(s, off);
        if (lane == 0) {
            float n = sqrtf(s);
            scale[row] = fminf(1.0f, 1.5f / fmaxf(n, 1e-7f));
            invn[row]  = (n > 0.f) ? 1.f / n : 0.f;
        }
    } else if (blk < 12500 + 720) {
        int b = blk - 12500;
        int wi = b / 144;
        int pos = (b % 144) * 256 + threadIdx.x;
        int n = pos / DIM, k = pos - n * DIM;
        float v;
        if      (wi == 0) v = vw1[(size_t)k * DIM + n];
        else if (wi == 1) v = vw2[(size_t)k * DIM + n];
        else if (wi == 2) v = w1W[pos];
        else if (wi == 3) v = w2W[pos];
        else              v = wg1W[pos];
        Wout[(size_t)wi * WMAT + pos] = f2bf(v);
    } else {
        int row = threadIdx.x;
        if (row <= LL) {
            float s = 0.f;
            const float* p = pe + row * PDIM;
            for (int d = 0; d < PDIM; ++d) { float v = p[d]; s += v * v; }
            float n = sqrtf(s);
            pscale[row] = fminf(1.0f, 1.5f / fmaxf(n, 1e-7f));
        }
    }
}

// ================= MEGAKERNEL (768 threads = 12 waves) =================
__global__ __launch_bounds__(768) void k_mega(
    const int* __restrict__ x, const int* __restrict__ pos,
    const float* __restrict__ emb, const float* __restrict__ pe,
    const float* __restrict__ scale, const float* __restrict__ pscale,
    const unsigned short* __restrict__ W16,
    const float* __restrict__ vw0, const float* __restrict__ vbias,
    const float* __restrict__ w1b, const float* __restrict__ w2b,
    const float* __restrict__ wg1b, const float* __restrict__ wg2W,
    const float* __restrict__ wg2b, const float* __restrict__ gq,
    const float* __restrict__ wA, const float* __restrict__ lng,
    const float* __restrict__ lnb, const float* __restrict__ wfW,
    const float* __restrict__ wfb, unsigned short* __restrict__ Cb16g) {

    __shared__ unsigned short Bs16[64 * DIM];   // swizzled: X16 -> S16 -> H16
    __shared__ unsigned short X16T[DIM * 72];   // X^T bf16 [d][j], cols 50..63 zero
    __shared__ unsigned short Ab16[64 * 72];    // attn weights bf16 [i][j]
    __shared__ float R1[LL * 196];              // K' -> parts[12][12][64]
    __shared__ float R2[LL * 196];              // Q -> S -> S2/S3
    __shared__ float xlast[DIM];
    __shared__ float GLs[DIM];
    __shared__ float cvec[3 * DIM];
    __shared__ float stB[DIM], sgB[DIM];
    __shared__ float red2[6][128];
    __shared__ float ags[64];
    __shared__ int   msk[64];
    __shared__ float was[64];
    __shared__ float red[12];
    __shared__ int   xi[LL], pii[LL];
    __shared__ float xsc[LL], psc[LL];

    const int b = blockIdx.x, t = threadIdx.x;
    const int wv = t >> 6, l = t & 63;
    const int lr = l & 15, lk = l >> 4;

    // ---- P0: indices, consts ----
    if (t < LL) {
        int v = x[b * LL + t];  xi[t] = v;  xsc[t] = scale[v];
        int pv = pos[b * LL + t]; pii[t] = pv; psc[t] = pscale[pv];
    }
    if (t >= 64 && t < 128) ags[t - 64] = 0.f;
    if (t >= 128 && t < 128 + LL) was[t - 128] = wA[t - 128];
    __syncthreads();
    if (t < 64) msk[t] = (t < LL) ? xi[t] : 0;
    // gather: wave per row, lane = d
    for (int r = wv; r < LL; r += 12) {
        float sx = xsc[r], sp = psc[r];
        float v0 = emb[(size_t)xi[r] * IDIM + l] * sx;
        float v1 = emb[(size_t)xi[r] * IDIM + l + 64] * sx;
        float v2 = pe[pii[r] * PDIM + l] * sp;
        int base = r * 384, sw = (r & 7) << 4;
        *(unsigned short*)((char*)Bs16 + ((base + l * 2) ^ sw))         = f2bf(v0);
        *(unsigned short*)((char*)Bs16 + ((base + (l + 64) * 2) ^ sw))  = f2bf(v1);
        *(unsigned short*)((char*)Bs16 + ((base + (l + 128) * 2) ^ sw)) = f2bf(v2);
        X16T[l * 72 + r]         = f2bf(v0);
        X16T[(l + 64) * 72 + r]  = f2bf(v1);
        X16T[(l + 128) * 72 + r] = f2bf(v2);
        if (r == 49) { xlast[l] = v0; xlast[l + 64] = v1; xlast[l + 128] = v2; }
    }
    // zero pads: Bs16 rows 50-63, X16T cols 50-63, Ab16 rows 50-63
    for (int e = t; e < 14 * DIM; e += 768) Bs16[LL * DIM + e] = 0;
    for (int e = t; e < DIM * 14; e += 768) { int d = e / 14, j = 50 + (e - d * 14); X16T[d * 72 + j] = 0; }
    for (int e = t; e < 14 * 72; e += 768) Ab16[50 * 72 + e] = 0;
    __syncthreads();

    // ---- GL = xlast @ wg2W^T + wg2b ----
    if (t < DIM) {
        float g = wg2b[t];
        const float* wr = wg2W + (size_t)t * DIM;
        float s0 = 0, s1 = 0, s2 = 0, s3 = 0;
        for (int k = 0; k < DIM; k += 4) {
            float4 w4 = *(const float4*)(wr + k);
            s0 += xlast[k] * w4.x; s1 += xlast[k + 1] * w4.y;
            s2 += xlast[k + 2] * w4.z; s3 += xlast[k + 3] * w4.w;
        }
        GLs[t] = g + ((s0 + s1) + (s2 + s3));
    }
    __syncthreads();

    // ---- P1: three GEMMs, per-mt streaming: K'->R1, Q->R2, Gpre->ags ----
    for (int task = wv; task < 36; task += 12) {
        int out = task / 12, nt = task % 12;
        int ncol = nt * 16 + lr;
        const unsigned short* bp = W16 + (size_t)(out == 0 ? 0 : (out == 1 ? 1 : 4)) * WMAT
                                   + (size_t)ncol * DIM + lk * 8;
#pragma unroll
        for (int mt = 0; mt < 4; ++mt) {
            int row = mt * 16 + lr;
            f32x4 ac = {};
#pragma unroll
            for (int ks = 0; ks < 6; ++ks) {
                int byte = (row * 384 + (lk * 8 + ks * 32) * 2) ^ ((row & 7) << 4);
                short8 af = *(const short8*)((const char*)Bs16 + byte);
                short8 bf = *(const short8*)(bp + ks * 32);
                ac = __builtin_amdgcn_mfma_f32_16x16x32_bf16(af, bf, ac, 0, 0, 0);
            }
            if (out == 0) {
                float bia = vbias[ncol];
#pragma unroll
                for (int r = 0; r < 4; ++r) {
                    int gr = mt * 16 + lk * 4 + r;
                    if (gr < LL) R1[gr * 196 + ncol] = ac[r] + bia;
                }
            } else if (out == 1) {
#pragma unroll
                for (int r = 0; r < 4; ++r) {
                    int gr = mt * 16 + lk * 4 + r;
                    if (gr < LL) R2[gr * 196 + ncol] = ac[r];
                }
            } else {
                float bia = wg1b[ncol] + GLs[ncol];
                float gqv = gq[ncol];
                int gr0 = mt * 16 + lk * 4;
                float v0 = ac[0] + bia, v1 = ac[1] + bia, v2 = ac[2] + bia, v3 = ac[3] + bia;
                float c0 = (gr0 + 0 < LL) ? gqv / (1.f + expf(-v0)) : 0.f;
                float c1 = (gr0 + 1 < LL) ? gqv / (1.f + expf(-v1)) : 0.f;
                float c2 = (gr0 + 2 < LL) ? gqv / (1.f + expf(-v2)) : 0.f;
                float c3 = (gr0 + 3 < LL) ? gqv / (1.f + expf(-v3)) : 0.f;
#pragma unroll
                for (int off = 1; off < 16; off <<= 1) {
                    c0 += __shfl_xor(c0, off); c1 += __shfl_xor(c1, off);
                    c2 += __shfl_xor(c2, off); c3 += __shfl_xor(c3, off);
                }
                if (lr == 0) {
                    if (gr0 + 0 < LL) atomicAdd(&ags[gr0 + 0], c0);
                    if (gr0 + 1 < LL) atomicAdd(&ags[gr0 + 1], c1);
                    if (gr0 + 2 < LL) atomicAdd(&ags[gr0 + 2], c2);
                    if (gr0 + 3 < LL) atomicAdd(&ags[gr0 + 3], c3);
                }
            }
        }
    }
    __syncthreads();

    // ---- P2: alpha + masked softmax -> Ab16 (12 waves x 16-dim slices) ----
    {
        const int d0 = wv * 16;
        float kr[16], wr[16];
        {
            const float* wp = vw0 + d0;
#pragma unroll
            for (int q = 0; q < 4; ++q) {
                float4 v = *(const float4*)(wp + q * 4);
                wr[q * 4] = v.x; wr[q * 4 + 1] = v.y; wr[q * 4 + 2] = v.z; wr[q * 4 + 3] = v.w;
            }
            if (l < LL) {
                const float* kp = R1 + l * 196 + d0;
#pragma unroll
                for (int q = 0; q < 4; ++q) {
                    float4 v = *(const float4*)(kp + q * 4);
                    kr[q * 4] = v.x; kr[q * 4 + 1] = v.y; kr[q * 4 + 2] = v.z; kr[q * 4 + 3] = v.w;
                }
            } else {
#pragma unroll
                for (int q = 0; q < 16; ++q) kr[q] = 0.f;
            }
        }
        __syncthreads();   // kr cached; R1 free -> parts
        float* parts = R1;              // [12][12][64] = 9216 floats <= 9800
        const float NEG = -__builtin_inff();
        bool valid = (l < LL) && (msk[l] != 0);
        for (int i0 = 0; i0 < LL; i0 += 12) {
            int cnt = (i0 + 12 <= LL) ? 12 : (LL - i0);
            for (int i = 0; i < cnt; ++i) {
                const float* qrow = R2 + (i0 + i) * 196 + d0;
                float b0 = 0, b1 = 0, b2 = 0, b3 = 0;
#pragma unroll
                for (int q = 0; q < 4; ++q) {
                    float4 qv = *(const float4*)(qrow + q * 4);
                    b0 += fmaxf(kr[q * 4 + 0] + qv.x, 0.f) * wr[q * 4 + 0];
                    b1 += fmaxf(kr[q * 4 + 1] + qv.y, 0.f) * wr[q * 4 + 1];
                    b2 += fmaxf(kr[q * 4 + 2] + qv.z, 0.f) * wr[q * 4 + 2];
                    b3 += fmaxf(kr[q * 4 + 3] + qv.w, 0.f) * wr[q * 4 + 3];
                }
                parts[(wv * 12 + i) * 64 + l] = (b0 + b1) + (b2 + b3);
            }
            __syncthreads();
            for (int i = wv; i < cnt; i += 12) {
                float aj = 0.f;
#pragma unroll
                for (int w2 = 0; w2 < 12; ++w2) aj += parts[(w2 * 12 + i) * 64 + l];
                if (!valid) aj = NEG;
                float m = aj;
#pragma unroll
                for (int off = 32; off; off >>= 1) m = fmaxf(m, __shfl_xor(m, off));
                float e = valid ? expf(aj - m) : 0.f;
                float s = e;
#pragma unroll
                for (int off = 32; off; off >>= 1) s += __shfl_xor(s, off);
                Ab16[(i0 + i) * 72 + l] = f2bf(e / s);   // 0 for l>=LL
            }
            __syncthreads();
        }
    }

    // ---- P3: S = Ab @ X via MFMA (A=Ab16, B=X16T) -> R2 f32 + Bs16 bf16 ----
    for (int task = wv; task < 48; task += 12) {
        int mt = task / 12, nt = task - (task / 12) * 12;
        int i0 = mt * 16, d0c = nt * 16;
        short8 aA0 = *(const short8*)(Ab16 + (i0 + lr) * 72 + lk * 8);
        short8 aA1 = *(const short8*)(Ab16 + (i0 + lr) * 72 + 32 + lk * 8);
        short8 bB0 = *(const short8*)(X16T + (d0c + lr) * 72 + lk * 8);
        short8 bB1 = *(const short8*)(X16T + (d0c + lr) * 72 + 32 + lk * 8);
        f32x4 ac = {};
        ac = __builtin_amdgcn_mfma_f32_16x16x32_bf16(aA0, bB0, ac, 0, 0, 0);
        ac = __builtin_amdgcn_mfma_f32_16x16x32_bf16(aA1, bB1, ac, 0, 0, 0);
        int d = d0c + lr;
#pragma unroll
        for (int r = 0; r < 4; ++r) {
            int i = i0 + lk * 4 + r;
            if (i < LL) {
                R2[i * 196 + d] = ac[r];
                int byte = (i * 384 + d * 2) ^ ((i & 7) << 4);
                *(unsigned short*)((char*)Bs16 + byte) = f2bf(ac[r]);
            }
        }
    }
    __syncthreads();

    // ---- P4: H2 = relu(S@w1 + b) -> Bs16 (per-mt streaming, 1 tile/wave) ----
    {
        f32x4 h[4] = {};
        {
            int ncol = wv * 16 + lr;
            const unsigned short* bp = W16 + (size_t)2 * WMAT + (size_t)ncol * DIM + lk * 8;
#pragma unroll
            for (int mt = 0; mt < 4; ++mt) {
                int row = mt * 16 + lr;
#pragma unroll
                for (int ks = 0; ks < 6; ++ks) {
                    int byte = (row * 384 + (lk * 8 + ks * 32) * 2) ^ ((row & 7) << 4);
                    short8 sf = *(const short8*)((const char*)Bs16 + byte);
                    short8 bf = *(const short8*)(bp + ks * 32);
                    h[mt] = __builtin_amdgcn_mfma_f32_16x16x32_bf16(sf, bf, h[mt], 0, 0, 0);
                }
            }
        }
        __syncthreads();   // all S16 reads done
        {
            int gc = wv * 16 + lr;
            float bia = w1b[gc];
#pragma unroll
            for (int mt = 0; mt < 4; ++mt)
#pragma unroll
                for (int r = 0; r < 4; ++r) {
                    int gr = mt * 16 + lk * 4 + r;
                    if (gr < LL) {
                        float v = fmaxf(h[mt][r] + bia, 0.f);
                        int byte = (gr * 384 + gc * 2) ^ ((gr & 7) << 4);
                        *(unsigned short*)((char*)Bs16 + byte) = f2bf(v);
                    }
                }
        }
    }
    __syncthreads();

    // ---- P5: S2 = H2@w2 + b + S (residual in-place in R2; per-mt streaming) ----
    {
        int ncol = wv * 16 + lr;
        const unsigned short* bp = W16 + (size_t)3 * WMAT + (size_t)ncol * DIM + lk * 8;
        float bia = w2b[ncol];
#pragma unroll
        for (int mt = 0; mt < 4; ++mt) {
            int row = mt * 16 + lr;
            f32x4 ac = {};
#pragma unroll
            for (int ks = 0; ks < 6; ++ks) {
                int byte = (row * 384 + (lk * 8 + ks * 32) * 2) ^ ((row & 7) << 4);
                short8 hf = *(const short8*)((const char*)Bs16 + byte);
                short8 bf = *(const short8*)(bp + ks * 32);
                ac = __builtin_amdgcn_mfma_f32_16x16x32_bf16(hf, bf, ac, 0, 0, 0);
            }
#pragma unroll
            for (int r = 0; r < 4; ++r) {
                int gr = mt * 16 + lk * 4 + r;
                if (gr < LL) R2[gr * 196 + ncol] = ac[r] + bia + R2[gr * 196 + ncol];
            }
        }
    }
    __syncthreads();

    // ---- P6: LayerNorm rows of R2 in place ----
    for (int r = wv; r < LL; r += 12) {
        float* p = R2 + r * 196;
        float v0 = p[l], v1 = p[l + 64], v2 = p[l + 128];
        float s = v0 + v1 + v2;
#pragma unroll
        for (int off = 32; off; off >>= 1) s += __shfl_xor(s, off);
        float mu = s * (1.f / DIM);
        float d0 = v0 - mu, d1 = v1 - mu, d2 = v2 - mu;
        float q = d0 * d0 + d1 * d1 + d2 * d2;
#pragma unroll
        for (int off = 32; off; off >>= 1) q += __shfl_xor(q, off);
        float inv = rsqrtf(q * (1.f / DIM) + EPS);
        p[l]       = lng[l] * d0 * inv + lnb[l];
        p[l + 64]  = lng[l + 64] * d1 * inv + lnb[l + 64];
        p[l + 128] = lng[l + 128] * d2 * inv + lnb[l + 128];
    }
    __syncthreads();

    // ---- P7: cvec = [ST, sl, SG], 4 groups x 192 threads ----
    if (t < DIM) {
        float st = 0.f;
        for (int p = 0; p < 25; ++p) st += was[p] * R2[p * 196 + t];
        cvec[t] = st;
        cvec[DIM + t] = xlast[t];
    } else if (t < 2 * DIM) {
        int d = t - DIM;
        float st = 0.f;
        for (int p = 25; p < LL; ++p) st += was[p] * R2[p * 196 + d];
        stB[d] = st;
    } else if (t < 3 * DIM) {
        int d = t - 2 * DIM;
        float sg = 0.f;
        const unsigned short* xr = X16T + d * 72;
        for (int p = 0; p < 25; ++p) sg += ags[p] * bf2f(xr[p]);
        cvec[2 * DIM + d] = sg;
    } else {
        int d = t - 3 * DIM;
        float sg = 0.f;
        const unsigned short* xr = X16T + d * 72;
        for (int p = 25; p < LL; ++p) sg += ags[p] * bf2f(xr[p]);
        sgB[d] = sg;
    }
    __syncthreads();
    if (t < DIM) {
        cvec[t] += stB[t];
        cvec[2 * DIM + t] += sgB[t];
    }
    __syncthreads();

    // ---- P8: c = normalize(selu(cvec @ wf^T + wf_b)) -> Cb16 global (6-way split) ----
    {
        int out = t & 127, part = t >> 7;       // part 0..5, 96 dims each
        float s = (part == 0) ? wfb[out] : 0.f;
        const float* wr = wfW + (size_t)out * (3 * DIM) + part * 96;
        const float* cv = cvec + part * 96;
        for (int e = 0; e < 96; e += 4) {
            float4 w4 = *(const float4*)(wr + e);
            s += cv[e] * w4.x + cv[e + 1] * w4.y + cv[e + 2] * w4.z + cv[e + 3] * w4.w;
        }
        red2[part][out] = s;
    }
    __syncthreads();
    float cj = 0.f;
    if (t < IDIM) {
        float s = red2[0][t] + red2[1][t] + red2[2][t]
                + red2[3][t] + red2[4][t] + red2[5][t];
        const float sa = 1.6732632423543772f, sc = 1.0507009873554805f;
        cj = sc * (s > 0.f ? s : sa * expm1f(s));
    }
    float sq = cj * cj;
#pragma unroll
    for (int off = 32; off; off >>= 1) sq += __shfl_xor(sq, off);
    if (l == 0 && wv < 2) red[wv] = sq;
    __syncthreads();
    if (t < IDIM) {
        float nrm = sqrtf(red[0] + red[1]);
        Cb16g[b * IDIM + t] = f2bf(cj / nrm);
    }
}

// ---------------- Z: block = 64n strip x full 256m, LDS-transposed coalesced stores ----------------
__global__ __launch_bounds__(256) void k_z4(const unsigned short* __restrict__ Cb16,
                                            const unsigned short* __restrict__ emb16,
                                            const float* __restrict__ invn,
                                            float* __restrict__ Z) {
    __shared__ float tr[4][64][68];
    int n0 = blockIdx.x * 64;
    int t = threadIdx.x, w = t >> 6, l = t & 63;
    int lr = l & 15, lk = l >> 4;

    short8 a[4][4];
#pragma unroll
    for (int mt = 0; mt < 4; ++mt) {
        int mrow = w * 64 + mt * 16 + lr;
        const unsigned short* ap = Cb16 + (size_t)mrow * IDIM + lk * 8;
#pragma unroll
        for (int ks = 0; ks < 4; ++ks) a[mt][ks] = *(const short8*)(ap + ks * 32);
    }
    f32x4 acc[4][4] = {};
#pragma unroll
    for (int nt = 0; nt < 4; ++nt) {
        int nrow = n0 + nt * 16 + lr;
        short8 bfr[4];
        if (nrow < NOUT) {
            const unsigned short* bp = emb16 + (size_t)(nrow + 1) * IDIM + lk * 8;
#pragma unroll
            for (int ks = 0; ks < 4; ++ks) bfr[ks] = *(const short8*)(bp + ks * 32);
        } else {
            short8 z = {};
#pragma unroll
            for (int ks = 0; ks < 4; ++ks) bfr[ks] = z;
        }
#pragma unroll
        for (int mt = 0; mt < 4; ++mt)
#pragma unroll
            for (int ks = 0; ks < 4; ++ks)
                acc[mt][nt] = __builtin_amdgcn_mfma_f32_16x16x32_bf16(a[mt][ks], bfr[ks], acc[mt][nt], 0, 0, 0);
    }
#pragma unroll
    for (int nt = 0; nt < 4; ++nt) {
        int gn = n0 + nt * 16 + lr;
        float sc = (gn < NOUT) ? WSC * invn[gn + 1] : 0.f;
#pragma unroll
        for (int mt = 0; mt < 4; ++mt)
#pragma unroll
            for (int r = 0; r < 4; ++r)
                tr[w][mt * 16 + lk * 4 + r][nt * 16 + lr] = acc[mt][nt][r] * sc;
    }
    __syncthreads();
    int q = l >> 4, s = l & 15;
    bool tail = (n0 + 64) > NOUT;
#pragma unroll
    for (int it = 0; it < 16; ++it) {
        int row = it * 4 + q;
        int gm  = w * 64 + row;
        float4 v = *(const float4*)&tr[w][row][s * 4];
        if (!tail) {
            *(float4*)&Z[(size_t)gm * NOUT + n0 + s * 4] = v;
        } else {
            int c0 = n0 + s * 4;
            float vv[4] = {v.x, v.y, v.z, v.w};
#pragma unroll
            for (int j = 0; j < 4; ++j)
                if (c0 + j < NOUT) Z[(size_t)gm * NOUT + c0 + j] = vv[j];
        }
    }
}

extern "C" void kernel_launch(void* const* d_in, const int* in_sizes, int n_in,
                              void* d_out, int out_size, void* d_ws, size_t ws_size,
                              hipStream_t stream) {
    const int*   x     = (const int*)d_in[0];
    const int*   pos   = (const int*)d_in[1];
    const float* emb   = (const float*)d_in[2];
    const float* pose  = (const float*)d_in[3];
    const float* vw0   = (const float*)d_in[4];
    const float* vw1   = (const float*)d_in[5];
    const float* vw2   = (const float*)d_in[6];
    const float* vbias = (const float*)d_in[7];
    const float* w1W   = (const float*)d_in[8];
    const float* w1b   = (const float*)d_in[9];
    const float* w2W   = (const float*)d_in[10];
    const float* w2b   = (const float*)d_in[11];
    const float* wA    = (const float*)d_in[12];
    const float* wg1W  = (const float*)d_in[13];
    const float* wg1b  = (const float*)d_in[14];
    const float* wg2W  = (const float*)d_in[15];
    const float* wg2b  = (const float*)d_in[16];
    const float* gq    = (const float*)d_in[17];
    const float* wfW   = (const float*)d_in[18];
    const float* wfb   = (const float*)d_in[19];
    const float* lng   = (const float*)d_in[20];
    const float* lnb   = (const float*)d_in[21];
    float* Z = (float*)d_out;

    float* w = (float*)d_ws;
    float* scale  = w; w += NITEMS;
    float* invn   = w; w += NITEMS;
    float* pscale = w; w += 64;
    w = (float*)(((uintptr_t)w + 15) & ~(uintptr_t)15);
    unsigned short* emb16 = (unsigned short*)w; w += (size_t)NITEMS * IDIM / 2;
    unsigned short* W16   = (unsigned short*)w; w += (size_t)5 * WMAT / 2;
    unsigned short* Cb16  = (unsigned short*)w; w += (size_t)BB * IDIM / 2;

    k_prep<<<12500 + 720 + 1, 256, 0, stream>>>(emb, scale, invn, emb16, pose, pscale,
                                                vw1, vw2, w1W, w2W, wg1W, W16);
    k_mega<<<BB, 768, 0, stream>>>(x, pos, emb, pose, scale, pscale, W16,
                                   vw0, vbias, w1b, w2b, wg1b, wg2W, wg2b, gq,
                                   wA, lng, lnb, wfW, wfb, Cb16);
    k_z4<<<(NOUT + 63) / 64, 256, 0, stream>>>(Cb16, emb16, invn, Z);
}

// Round 17
// 100.986 us; speedup vs baseline: 1.6057x; 1.0030x over previous
//
#include <hip/hip_runtime.h>
#include <hip/hip_bf16.h>
#include <math.h>
#include <stdint.h>

#define BB 256
#define LL 50
#define IDIM 128
#define PDIM 64
#define DIM 192
#define NITEMS 50000
#define NOUT 49999
#define WSC 20.0f
#define EPS 1e-5f
#define WMAT (DIM * DIM)

typedef __attribute__((ext_vector_type(8))) short  short8;
typedef __attribute__((ext_vector_type(4))) float  f32x4;

__device__ __forceinline__ unsigned short f2bf(float f) {
    unsigned int u = __float_as_uint(f);
    u = (u + 0x7FFFu + ((u >> 16) & 1u)) >> 16;
    return (unsigned short)u;
}
__device__ __forceinline__ float bf2f(unsigned short u) {
    unsigned int v = ((unsigned int)u) << 16;
    return __uint_as_float(v);
}

// ---------------- fused prep: emb norms+bf16 | weight cvt | pos norms ----------------
__global__ __launch_bounds__(256) void k_prep(const float* __restrict__ emb,
                                              float* __restrict__ scale,
                                              float* __restrict__ invn,
                                              unsigned short* __restrict__ emb16,
                                              const float* __restrict__ pe,
                                              float* __restrict__ pscale,
                                              const float* __restrict__ vw1, const float* __restrict__ vw2,
                                              const float* __restrict__ w1W, const float* __restrict__ w2W,
                                              const float* __restrict__ wg1W,
                                              unsigned short* __restrict__ Wout) {
    int blk = blockIdx.x;
    if (blk < 12500) {
        int row  = blk * 4 + (threadIdx.x >> 6);
        int lane = threadIdx.x & 63;
        const float* p = emb + (size_t)row * IDIM;
        float a = p[lane], b = p[lane + 64];
        emb16[(size_t)row * IDIM + lane]      = f2bf(a);
        emb16[(size_t)row * IDIM + lane + 64] = f2bf(b);
        float s = a * a + b * b;
#pragma unroll
        for (int off = 32; off; off >>= 1) s += __shfl_xor(s, off);
        if (lane == 0) {
            float n = sqrtf(s);
            scale[row] = fminf(1.0f, 1.5f / fmaxf(n, 1e-7f));
            invn[row]  = (n > 0.f) ? 1.f / n : 0.f;
        }
    } else if (blk < 12500 + 720) {
        int b = blk - 12500;
        int wi = b / 144;
        int pos = (b % 144) * 256 + threadIdx.x;
        int n = pos / DIM, k = pos - n * DIM;
        float v;
        if      (wi == 0) v = vw1[(size_t)k * DIM + n];
        else if (wi == 1) v = vw2[(size_t)k * DIM + n];
        else if (wi == 2) v = w1W[pos];
        else if (wi == 3) v = w2W[pos];
        else              v = wg1W[pos];
        Wout[(size_t)wi * WMAT + pos] = f2bf(v);
    } else {
        int row = threadIdx.x;
        if (row <= LL) {
            float s = 0.f;
            const float* p = pe + row * PDIM;
            for (int d = 0; d < PDIM; ++d) { float v = p[d]; s += v * v; }
            float n = sqrtf(s);
            pscale[row] = fminf(1.0f, 1.5f / fmaxf(n, 1e-7f));
        }
    }
}

// ================= MEGAKERNEL (768 threads = 12 waves, 3 waves/EU) =================
__global__ __launch_bounds__(768, 3) void k_mega(
    const int* __restrict__ x, const int* __restrict__ pos,
    const float* __restrict__ emb, const float* __restrict__ pe,
    const float* __restrict__ scale, const float* __restrict__ pscale,
    const unsigned short* __restrict__ W16,
    const float* __restrict__ vw0, const float* __restrict__ vbias,
    const float* __restrict__ w1b, const float* __restrict__ w2b,
    const float* __restrict__ wg1b, const float* __restrict__ wg2W,
    const float* __restrict__ wg2b, const float* __restrict__ gq,
    const float* __restrict__ wA, const float* __restrict__ lng,
    const float* __restrict__ lnb, const float* __restrict__ wfW,
    const float* __restrict__ wfb, unsigned short* __restrict__ Cb16g) {

    __shared__ unsigned short Bs16[64 * DIM];   // swizzled: X16 -> S16 -> H16
    __shared__ unsigned short X16T[DIM * 72];   // X^T bf16 [d][j], cols 50..63 zero
    __shared__ unsigned short Ab16[64 * 72];    // attn weights bf16 [i][j]
    __shared__ float R1[LL * 196];              // K' -> parts16[12][25][64] (bf16)
    __shared__ float R2[LL * 196];              // Q -> S -> S2/S3
    __shared__ float xlast[DIM];
    __shared__ float GLs[DIM];
    __shared__ float cvec[3 * DIM];
    __shared__ float stB[DIM], sgB[DIM];
    __shared__ float red2[6][128];
    __shared__ float ags[64];
    __shared__ int   msk[64];
    __shared__ float was[64];
    __shared__ float red[12];
    __shared__ int   xi[LL], pii[LL];
    __shared__ float xsc[LL], psc[LL];

    const int b = blockIdx.x, t = threadIdx.x;
    const int wv = t >> 6, l = t & 63;
    const int lr = l & 15, lk = l >> 4;

    // ---- P0: indices, consts ----
    if (t < LL) {
        int v = x[b * LL + t];  xi[t] = v;  xsc[t] = scale[v];
        int pv = pos[b * LL + t]; pii[t] = pv; psc[t] = pscale[pv];
    }
    if (t >= 64 && t < 128) ags[t - 64] = 0.f;
    if (t >= 128 && t < 128 + LL) was[t - 128] = wA[t - 128];
    __syncthreads();
    if (t < 64) msk[t] = (t < LL) ? xi[t] : 0;
    // gather: wave per row, lane = d
    for (int r = wv; r < LL; r += 12) {
        float sx = xsc[r], sp = psc[r];
        float v0 = emb[(size_t)xi[r] * IDIM + l] * sx;
        float v1 = emb[(size_t)xi[r] * IDIM + l + 64] * sx;
        float v2 = pe[pii[r] * PDIM + l] * sp;
        int base = r * 384, sw = (r & 7) << 4;
        *(unsigned short*)((char*)Bs16 + ((base + l * 2) ^ sw))         = f2bf(v0);
        *(unsigned short*)((char*)Bs16 + ((base + (l + 64) * 2) ^ sw))  = f2bf(v1);
        *(unsigned short*)((char*)Bs16 + ((base + (l + 128) * 2) ^ sw)) = f2bf(v2);
        X16T[l * 72 + r]         = f2bf(v0);
        X16T[(l + 64) * 72 + r]  = f2bf(v1);
        X16T[(l + 128) * 72 + r] = f2bf(v2);
        if (r == 49) { xlast[l] = v0; xlast[l + 64] = v1; xlast[l + 128] = v2; }
    }
    // zero pads: Bs16 rows 50-63, X16T cols 50-63, Ab16 rows 50-63
    for (int e = t; e < 14 * DIM; e += 768) Bs16[LL * DIM + e] = 0;
    for (int e = t; e < DIM * 14; e += 768) { int d = e / 14, j = 50 + (e - d * 14); X16T[d * 72 + j] = 0; }
    for (int e = t; e < 14 * 72; e += 768) Ab16[50 * 72 + e] = 0;
    __syncthreads();

    // ---- GL = xlast @ wg2W^T + wg2b ----
    if (t < DIM) {
        float g = wg2b[t];
        const float* wr = wg2W + (size_t)t * DIM;
        float s0 = 0, s1 = 0, s2 = 0, s3 = 0;
        for (int k = 0; k < DIM; k += 4) {
            float4 w4 = *(const float4*)(wr + k);
            s0 += xlast[k] * w4.x; s1 += xlast[k + 1] * w4.y;
            s2 += xlast[k + 2] * w4.z; s3 += xlast[k + 3] * w4.w;
        }
        GLs[t] = g + ((s0 + s1) + (s2 + s3));
    }
    __syncthreads();

    // ---- P1: three GEMMs, per-mt streaming: K'->R1, Q->R2, Gpre->ags ----
    for (int task = wv; task < 36; task += 12) {
        int out = task / 12, nt = task % 12;
        int ncol = nt * 16 + lr;
        const unsigned short* bp = W16 + (size_t)(out == 0 ? 0 : (out == 1 ? 1 : 4)) * WMAT
                                   + (size_t)ncol * DIM + lk * 8;
#pragma unroll
        for (int mt = 0; mt < 4; ++mt) {
            int row = mt * 16 + lr;
            f32x4 ac = {};
#pragma unroll
            for (int ks = 0; ks < 6; ++ks) {
                int byte = (row * 384 + (lk * 8 + ks * 32) * 2) ^ ((row & 7) << 4);
                short8 af = *(const short8*)((const char*)Bs16 + byte);
                short8 bf = *(const short8*)(bp + ks * 32);
                ac = __builtin_amdgcn_mfma_f32_16x16x32_bf16(af, bf, ac, 0, 0, 0);
            }
            if (out == 0) {
                float bia = vbias[ncol];
#pragma unroll
                for (int r = 0; r < 4; ++r) {
                    int gr = mt * 16 + lk * 4 + r;
                    if (gr < LL) R1[gr * 196 + ncol] = ac[r] + bia;
                }
            } else if (out == 1) {
#pragma unroll
                for (int r = 0; r < 4; ++r) {
                    int gr = mt * 16 + lk * 4 + r;
                    if (gr < LL) R2[gr * 196 + ncol] = ac[r];
                }
            } else {
                float bia = wg1b[ncol] + GLs[ncol];
                float gqv = gq[ncol];
                int gr0 = mt * 16 + lk * 4;
                float v0 = ac[0] + bia, v1 = ac[1] + bia, v2 = ac[2] + bia, v3 = ac[3] + bia;
                float c0 = (gr0 + 0 < LL) ? gqv / (1.f + expf(-v0)) : 0.f;
                float c1 = (gr0 + 1 < LL) ? gqv / (1.f + expf(-v1)) : 0.f;
                float c2 = (gr0 + 2 < LL) ? gqv / (1.f + expf(-v2)) : 0.f;
                float c3 = (gr0 + 3 < LL) ? gqv / (1.f + expf(-v3)) : 0.f;
#pragma unroll
                for (int off = 1; off < 16; off <<= 1) {
                    c0 += __shfl_xor(c0, off); c1 += __shfl_xor(c1, off);
                    c2 += __shfl_xor(c2, off); c3 += __shfl_xor(c3, off);
                }
                if (lr == 0) {
                    if (gr0 + 0 < LL) atomicAdd(&ags[gr0 + 0], c0);
                    if (gr0 + 1 < LL) atomicAdd(&ags[gr0 + 1], c1);
                    if (gr0 + 2 < LL) atomicAdd(&ags[gr0 + 2], c2);
                    if (gr0 + 3 < LL) atomicAdd(&ags[gr0 + 3], c3);
                }
            }
        }
    }
    __syncthreads();

    // ---- P2: alpha + masked softmax -> Ab16 (12 waves x 16-dim slices, 2x25 chunks, bf16 parts) ----
    {
        const int d0 = wv * 16;
        float kr[16], wr[16];
        {
            const float* wp = vw0 + d0;
#pragma unroll
            for (int q = 0; q < 4; ++q) {
                float4 v = *(const float4*)(wp + q * 4);
                wr[q * 4] = v.x; wr[q * 4 + 1] = v.y; wr[q * 4 + 2] = v.z; wr[q * 4 + 3] = v.w;
            }
            if (l < LL) {
                const float* kp = R1 + l * 196 + d0;
#pragma unroll
                for (int q = 0; q < 4; ++q) {
                    float4 v = *(const float4*)(kp + q * 4);
                    kr[q * 4] = v.x; kr[q * 4 + 1] = v.y; kr[q * 4 + 2] = v.z; kr[q * 4 + 3] = v.w;
                }
            } else {
#pragma unroll
                for (int q = 0; q < 16; ++q) kr[q] = 0.f;
            }
        }
        __syncthreads();   // kr cached; R1 free -> parts16
        unsigned short* parts16 = (unsigned short*)R1;   // [12][25][64] bf16 = 38400 B
        const float NEG = -__builtin_inff();
        bool valid = (l < LL) && (msk[l] != 0);
#pragma unroll
        for (int i0 = 0; i0 < LL; i0 += 25) {
            for (int i = 0; i < 25; ++i) {
                const float* qrow = R2 + (i0 + i) * 196 + d0;
                float b0 = 0, b1 = 0, b2 = 0, b3 = 0;
#pragma unroll
                for (int q = 0; q < 4; ++q) {
                    float4 qv = *(const float4*)(qrow + q * 4);
                    b0 += fmaxf(kr[q * 4 + 0] + qv.x, 0.f) * wr[q * 4 + 0];
                    b1 += fmaxf(kr[q * 4 + 1] + qv.y, 0.f) * wr[q * 4 + 1];
                    b2 += fmaxf(kr[q * 4 + 2] + qv.z, 0.f) * wr[q * 4 + 2];
                    b3 += fmaxf(kr[q * 4 + 3] + qv.w, 0.f) * wr[q * 4 + 3];
                }
                parts16[(wv * 25 + i) * 64 + l] = f2bf((b0 + b1) + (b2 + b3));
            }
            __syncthreads();
            for (int i = wv; i < 25; i += 12) {
                float aj = 0.f;
#pragma unroll
                for (int w2 = 0; w2 < 12; ++w2) aj += bf2f(parts16[(w2 * 25 + i) * 64 + l]);
                if (!valid) aj = NEG;
                float m = aj;
#pragma unroll
                for (int off = 32; off; off >>= 1) m = fmaxf(m, __shfl_xor(m, off));
                float e = valid ? expf(aj - m) : 0.f;
                float s = e;
#pragma unroll
                for (int off = 32; off; off >>= 1) s += __shfl_xor(s, off);
                Ab16[(i0 + i) * 72 + l] = f2bf(e / s);   // 0 for l>=LL
            }
            __syncthreads();
        }
    }

    // ---- P3: S = Ab @ X via MFMA (A=Ab16, B=X16T) -> R2 f32 + Bs16 bf16 ----
    for (int task = wv; task < 48; task += 12) {
        int mt = task / 12, nt = task - (task / 12) * 12;
        int i0 = mt * 16, d0c = nt * 16;
        short8 aA0 = *(const short8*)(Ab16 + (i0 + lr) * 72 + lk * 8);
        short8 aA1 = *(const short8*)(Ab16 + (i0 + lr) * 72 + 32 + lk * 8);
        short8 bB0 = *(const short8*)(X16T + (d0c + lr) * 72 + lk * 8);
        short8 bB1 = *(const short8*)(X16T + (d0c + lr) * 72 + 32 + lk * 8);
        f32x4 ac = {};
        ac = __builtin_amdgcn_mfma_f32_16x16x32_bf16(aA0, bB0, ac, 0, 0, 0);
        ac = __builtin_amdgcn_mfma_f32_16x16x32_bf16(aA1, bB1, ac, 0, 0, 0);
        int d = d0c + lr;
#pragma unroll
        for (int r = 0; r < 4; ++r) {
            int i = i0 + lk * 4 + r;
            if (i < LL) {
                R2[i * 196 + d] = ac[r];
                int byte = (i * 384 + d * 2) ^ ((i & 7) << 4);
                *(unsigned short*)((char*)Bs16 + byte) = f2bf(ac[r]);
            }
        }
    }
    __syncthreads();

    // ---- P4: H2 = relu(S@w1 + b) -> Bs16 (per-mt streaming, 1 tile/wave) ----
    {
        f32x4 h[4] = {};
        {
            int ncol = wv * 16 + lr;
            const unsigned short* bp = W16 + (size_t)2 * WMAT + (size_t)ncol * DIM + lk * 8;
#pragma unroll
            for (int mt = 0; mt < 4; ++mt) {
                int row = mt * 16 + lr;
#pragma unroll
                for (int ks = 0; ks < 6; ++ks) {
                    int byte = (row * 384 + (lk * 8 + ks * 32) * 2) ^ ((row & 7) << 4);
                    short8 sf = *(const short8*)((const char*)Bs16 + byte);
                    short8 bf = *(const short8*)(bp + ks * 32);
                    h[mt] = __builtin_amdgcn_mfma_f32_16x16x32_bf16(sf, bf, h[mt], 0, 0, 0);
                }
            }
        }
        __syncthreads();   // all S16 reads done
        {
            int gc = wv * 16 + lr;
            float bia = w1b[gc];
#pragma unroll
            for (int mt = 0; mt < 4; ++mt)
#pragma unroll
                for (int r = 0; r < 4; ++r) {
                    int gr = mt * 16 + lk * 4 + r;
                    if (gr < LL) {
                        float v = fmaxf(h[mt][r] + bia, 0.f);
                        int byte = (gr * 384 + gc * 2) ^ ((gr & 7) << 4);
                        *(unsigned short*)((char*)Bs16 + byte) = f2bf(v);
                    }
                }
        }
    }
    __syncthreads();

    // ---- P5: S2 = H2@w2 + b + S (residual in-place in R2; per-mt streaming) ----
    {
        int ncol = wv * 16 + lr;
        const unsigned short* bp = W16 + (size_t)3 * WMAT + (size_t)ncol * DIM + lk * 8;
        float bia = w2b[ncol];
#pragma unroll
        for (int mt = 0; mt < 4; ++mt) {
            int row = mt * 16 + lr;
            f32x4 ac = {};
#pragma unroll
            for (int ks = 0; ks < 6; ++ks) {
                int byte = (row * 384 + (lk * 8 + ks * 32) * 2) ^ ((row & 7) << 4);
                short8 hf = *(const short8*)((const char*)Bs16 + byte);
                short8 bf = *(const short8*)(bp + ks * 32);
                ac = __builtin_amdgcn_mfma_f32_16x16x32_bf16(hf, bf, ac, 0, 0, 0);
            }
#pragma unroll
            for (int r = 0; r < 4; ++r) {
                int gr = mt * 16 + lk * 4 + r;
                if (gr < LL) R2[gr * 196 + ncol] = ac[r] + bia + R2[gr * 196 + ncol];
            }
        }
    }
    __syncthreads();

    // ---- P6: LayerNorm rows of R2 in place ----
    for (int r = wv; r < LL; r += 12) {
        float* p = R2 + r * 196;
        float v0 = p[l], v1 = p[l + 64], v2 = p[l + 128];
        float s = v0 + v1 + v2;
#pragma unroll
        for (int off = 32; off; off >>= 1) s += __shfl_xor(s, off);
        float mu = s * (1.f / DIM);
        float d0 = v0 - mu, d1 = v1 - mu, d2 = v2 - mu;
        float q = d0 * d0 + d1 * d1 + d2 * d2;
#pragma unroll
        for (int off = 32; off; off >>= 1) q += __shfl_xor(q, off);
        float inv = rsqrtf(q * (1.f / DIM) + EPS);
        p[l]       = lng[l] * d0 * inv + lnb[l];
        p[l + 64]  = lng[l + 64] * d1 * inv + lnb[l + 64];
        p[l + 128] = lng[l + 128] * d2 * inv + lnb[l + 128];
    }
    __syncthreads();

    // ---- P7: cvec = [ST, sl, SG], 4 groups x 192 threads ----
    if (t < DIM) {
        float st = 0.f;
        for (int p = 0; p < 25; ++p) st += was[p] * R2[p * 196 + t];
        cvec[t] = st;
        cvec[DIM + t] = xlast[t];
    } else if (t < 2 * DIM) {
        int d = t - DIM;
        float st = 0.f;
        for (int p = 25; p < LL; ++p) st += was[p] * R2[p * 196 + d];
        stB[d] = st;
    } else if (t < 3 * DIM) {
        int d = t - 2 * DIM;
        float sg = 0.f;
        const unsigned short* xr = X16T + d * 72;
        for (int p = 0; p < 25; ++p) sg += ags[p] * bf2f(xr[p]);
        cvec[2 * DIM + d] = sg;
    } else {
        int d = t - 3 * DIM;
        float sg = 0.f;
        const unsigned short* xr = X16T + d * 72;
        for (int p = 25; p < LL; ++p) sg += ags[p] * bf2f(xr[p]);
        sgB[d] = sg;
    }
    __syncthreads();
    if (t < DIM) {
        cvec[t] += stB[t];
        cvec[2 * DIM + t] += sgB[t];
    }
    __syncthreads();

    // ---- P8: c = normalize(selu(cvec @ wf^T + wf_b)) -> Cb16 global (6-way split) ----
    {
        int out = t & 127, part = t >> 7;       // part 0..5, 96 dims each
        float s = (part == 0) ? wfb[out] : 0.f;
        const float* wr = wfW + (size_t)out * (3 * DIM) + part * 96;
        const float* cv = cvec + part * 96;
        for (int e = 0; e < 96; e += 4) {
            float4 w4 = *(const float4*)(wr + e);
            s += cv[e] * w4.x + cv[e + 1] * w4.y + cv[e + 2] * w4.z + cv[e + 3] * w4.w;
        }
        red2[part][out] = s;
    }
    __syncthreads();
    float cj = 0.f;
    if (t < IDIM) {
        float s = red2[0][t] + red2[1][t] + red2[2][t]
                + red2[3][t] + red2[4][t] + red2[5][t];
        const float sa = 1.6732632423543772f, sc = 1.0507009873554805f;
        cj = sc * (s > 0.f ? s : sa * expm1f(s));
    }
    float sq = cj * cj;
#pragma unroll
    for (int off = 32; off; off >>= 1) sq += __shfl_xor(sq, off);
    if (l == 0 && wv < 2) red[wv] = sq;
    __syncthreads();
    if (t < IDIM) {
        float nrm = sqrtf(red[0] + red[1]);
        Cb16g[b * IDIM + t] = f2bf(cj / nrm);
    }
}

// ---------------- Z: block = 64n strip x full 256m, LDS-transposed coalesced stores ----------------
__global__ __launch_bounds__(256) void k_z4(const unsigned short* __restrict__ Cb16,
                                            const unsigned short* __restrict__ emb16,
                                            const float* __restrict__ invn,
                                            float* __restrict__ Z) {
    __shared__ float tr[4][64][68];
    int n0 = blockIdx.x * 64;
    int t = threadIdx.x, w = t >> 6, l = t & 63;
    int lr = l & 15, lk = l >> 4;

    short8 a[4][4];
#pragma unroll
    for (int mt = 0; mt < 4; ++mt) {
        int mrow = w * 64 + mt * 16 + lr;
        const unsigned short* ap = Cb16 + (size_t)mrow * IDIM + lk * 8;
#pragma unroll
        for (int ks = 0; ks < 4; ++ks) a[mt][ks] = *(const short8*)(ap + ks * 32);
    }
    f32x4 acc[4][4] = {};
#pragma unroll
    for (int nt = 0; nt < 4; ++nt) {
        int nrow = n0 + nt * 16 + lr;
        short8 bfr[4];
        if (nrow < NOUT) {
            const unsigned short* bp = emb16 + (size_t)(nrow + 1) * IDIM + lk * 8;
#pragma unroll
            for (int ks = 0; ks < 4; ++ks) bfr[ks] = *(const short8*)(bp + ks * 32);
        } else {
            short8 z = {};
#pragma unroll
            for (int ks = 0; ks < 4; ++ks) bfr[ks] = z;
        }
#pragma unroll
        for (int mt = 0; mt < 4; ++mt)
#pragma unroll
            for (int ks = 0; ks < 4; ++ks)
                acc[mt][nt] = __builtin_amdgcn_mfma_f32_16x16x32_bf16(a[mt][ks], bfr[ks], acc[mt][nt], 0, 0, 0);
    }
#pragma unroll
    for (int nt = 0; nt < 4; ++nt) {
        int gn = n0 + nt * 16 + lr;
        float sc = (gn < NOUT) ? WSC * invn[gn + 1] : 0.f;
#pragma unroll
        for (int mt = 0; mt < 4; ++mt)
#pragma unroll
            for (int r = 0; r < 4; ++r)
                tr[w][mt * 16 + lk * 4 + r][nt * 16 + lr] = acc[mt][nt][r] * sc;
    }
    __syncthreads();
    int q = l >> 4, s = l & 15;
    bool tail = (n0 + 64) > NOUT;
#pragma unroll
    for (int it = 0; it < 16; ++it) {
        int row = it * 4 + q;
        int gm  = w * 64 + row;
        float4 v = *(const float4*)&tr[w][row][s * 4];
        if (!tail) {
            *(float4*)&Z[(size_t)gm * NOUT + n0 + s * 4] = v;
        } else {
            int c0 = n0 + s * 4;
            float vv[4] = {v.x, v.y, v.z, v.w};
#pragma unroll
            for (int j = 0; j < 4; ++j)
                if (c0 + j < NOUT) Z[(size_t)gm * NOUT + c0 + j] = vv[j];
        }
    }
}

extern "C" void kernel_launch(void* const* d_in, const int* in_sizes, int n_in,
                              void* d_out, int out_size, void* d_ws, size_t ws_size,
                              hipStream_t stream) {
    const int*   x     = (const int*)d_in[0];
    const int*   pos   = (const int*)d_in[1];
    const float* emb   = (const float*)d_in[2];
    const float* pose  = (const float*)d_in[3];
    const float* vw0   = (const float*)d_in[4];
    const float* vw1   = (const float*)d_in[5];
    const float* vw2   = (const float*)d_in[6];
    const float* vbias = (const float*)d_in[7];
    const float* w1W   = (const float*)d_in[8];
    const float* w1b   = (const float*)d_in[9];
    const float* w2W   = (const float*)d_in[10];
    const float* w2b   = (const float*)d_in[11];
    const float* wA    = (const float*)d_in[12];
    const float* wg1W  = (const float*)d_in[13];
    const float* wg1b  = (const float*)d_in[14];
    const float* wg2W  = (const float*)d_in[15];
    const float* wg2b  = (const float*)d_in[16];
    const float* gq    = (const float*)d_in[17];
    const float* wfW   = (const float*)d_in[18];
    const float* wfb   = (const float*)d_in[19];
    const float* lng   = (const float*)d_in[20];
    const float* lnb   = (const float*)d_in[21];
    float* Z = (float*)d_out;

    float* w = (float*)d_ws;
    float* scale  = w; w += NITEMS;
    float* invn   = w; w += NITEMS;
    float* pscale = w; w += 64;
    w = (float*)(((uintptr_t)w + 15) & ~(uintptr_t)15);
    unsigned short* emb16 = (unsigned short*)w; w += (size_t)NITEMS * IDIM / 2;
    unsigned short* W16   = (unsigned short*)w; w += (size_t)5 * WMAT / 2;
    unsigned short* Cb16  = (unsigned short*)w; w += (size_t)BB * IDIM / 2;

    k_prep<<<12500 + 720 + 1, 256, 0, stream>>>(emb, scale, invn, emb16, pose, pscale,
                                                vw1, vw2, w1W, w2W, wg1W, W16);
    k_mega<<<BB, 768, 0, stream>>>(x, pos, emb, pose, scale, pscale, W16,
                                   vw0, vbias, w1b, w2b, wg1b, wg2W, wg2b, gq,
                                   wA, lng, lnb, wfW, wfb, Cb16);
    k_z4<<<(NOUT + 63) / 64, 256, 0, stream>>>(Cb16, emb16, invn, Z);
}